// Round 11
// baseline (181.772 us; speedup 1.0000x reference)
//
#include <hip/hip_runtime.h>
#include <hip/hip_bf16.h>

typedef short bf16x8 __attribute__((ext_vector_type(8)));  // 8 bf16 (4 VGPRs)
typedef float f32x4 __attribute__((ext_vector_type(4)));

#define S_LEN 2048
#define NHEAD 16
#define DM 1024

#if __has_builtin(__builtin_amdgcn_exp2f)
#define EXP2(x) __builtin_amdgcn_exp2f(x)
#else
#define EXP2(x) exp2f(x)
#endif

__device__ __forceinline__ short f2bf(float f) {
  union { float f; unsigned u; } x; x.f = f;
  unsigned r = x.u + 0x7fffu + ((x.u >> 16) & 1u);  // RNE
  return (short)(r >> 16);
}

__device__ __forceinline__ unsigned cvt_pk_bf16(float lo, float hi) {
  unsigned r;
  asm("v_cvt_pk_bf16_f32 %0, %1, %2" : "=v"(r) : "v"(lo), "v"(hi));
  return r;
}

__device__ __forceinline__ void pl32swap(unsigned& a, unsigned& b) {
#if __has_builtin(__builtin_amdgcn_permlane32_swap)
  auto r = __builtin_amdgcn_permlane32_swap(a, b, false, false);
  a = r[0]; b = r[1];
#else
  asm volatile("v_permlane32_swap_b32 %0, %1" : "+v"(a), "+v"(b));
#endif
}
__device__ __forceinline__ void pl16swap(unsigned& a, unsigned& b) {
#if __has_builtin(__builtin_amdgcn_permlane16_swap)
  auto r = __builtin_amdgcn_permlane16_swap(a, b, false, false);
  a = r[0]; b = r[1];
#else
  asm volatile("v_permlane16_swap_b32 %0, %1" : "+v"(a), "+v"(b));
#endif
}

__device__ __forceinline__ void gload16(const void* g, void* l) {
  __builtin_amdgcn_global_load_lds(
      (const __attribute__((address_space(1))) void*)g,
      (__attribute__((address_space(3))) void*)l, 16, 0, 0);
}

// 3-piece partial-O addressing (f32 rows of 1024)
__device__ __forceinline__ float* op_row(float* p0, float* p1, float* p2, int tok) {
  if (tok < 2048) return p0 + (size_t)tok * 1024;
  if (tok < 3584) return p1 + (size_t)(tok - 2048) * 1024;
  return p2 + (size_t)(tok - 3584) * 1024;
}

// ---------------- weight transpose+convert; z==4: mask -> bf16 table Mb
__global__ __launch_bounds__(256) void wtrans(const float* __restrict__ Wq, const float* __restrict__ Wk,
                                              const float* __restrict__ Wv, const float* __restrict__ Wo,
                                              const int* __restrict__ mask,
                                              short* Tq, short* Tk, short* Tv, short* To, short* Mb) {
  const int z = blockIdx.z;
  const int tid = threadIdx.x;
  if (z == 4) {
    if (blockIdx.y == 0 && blockIdx.x < 16) {
      int i = blockIdx.x * 256 + tid;
      Mb[i] = mask[i] ? (short)0x3F80 : (short)0;  // bf16 1.0 / 0.0
    }
    return;
  }
  const float* W = (z == 0) ? Wq : (z == 1) ? Wk : (z == 2) ? Wv : Wo;
  short* T = (z == 0) ? Tq : (z == 1) ? Tk : (z == 2) ? Tv : To;
  __shared__ short Tl[64][72];
  const int k0 = blockIdx.x * 64, n0 = blockIdx.y * 64;
  const int r = tid >> 2, c0 = (tid & 3) * 16;
#pragma unroll
  for (int j = 0; j < 4; j++) {
    float4 v = *(const float4*)&W[(size_t)(k0 + r) * DM + n0 + c0 + 4 * j];
    Tl[r][c0 + 4 * j + 0] = f2bf(v.x);
    Tl[r][c0 + 4 * j + 1] = f2bf(v.y);
    Tl[r][c0 + 4 * j + 2] = f2bf(v.z);
    Tl[r][c0 + 4 * j + 3] = f2bf(v.w);
  }
  __syncthreads();
  bf16x8 o0, o1;
#pragma unroll
  for (int j = 0; j < 8; j++) { o0[j] = Tl[c0 + j][r]; o1[j] = Tl[c0 + 8 + j][r]; }
  *(bf16x8*)&T[(size_t)(n0 + r) * DM + k0 + c0] = o0;
  *(bf16x8*)&T[(size_t)(n0 + r) * DM + k0 + c0 + 8] = o1;
}

// ---------------- x f32 -> bf16 convert (3 tensors)
__global__ __launch_bounds__(256) void xcvt(const float* __restrict__ q, const float* __restrict__ k,
                                            const float* __restrict__ v,
                                            short* xq, short* xk, short* xv) {
  const int z = blockIdx.y;
  const float* src = (z == 0) ? q : (z == 1) ? k : v;
  short* dst = (z == 0) ? xq : (z == 1) ? xk : xv;
  const size_t base = ((size_t)blockIdx.x * 256 + threadIdx.x) * 16;
  float4 a = *(const float4*)&src[base];
  float4 b = *(const float4*)&src[base + 4];
  float4 c = *(const float4*)&src[base + 8];
  float4 d = *(const float4*)&src[base + 12];
  bf16x8 o0, o1;
  o0[0] = f2bf(a.x); o0[1] = f2bf(a.y); o0[2] = f2bf(a.z); o0[3] = f2bf(a.w);
  o0[4] = f2bf(b.x); o0[5] = f2bf(b.y); o0[6] = f2bf(b.z); o0[7] = f2bf(b.w);
  o1[0] = f2bf(c.x); o1[1] = f2bf(c.y); o1[2] = f2bf(c.z); o1[3] = f2bf(c.w);
  o1[4] = f2bf(d.x); o1[5] = f2bf(d.y); o1[6] = f2bf(d.z); o1[7] = f2bf(d.w);
  *(bf16x8*)&dst[base] = o0;
  *(bf16x8*)&dst[base + 8] = o1;
}

// ---------------- gemm3: all-bf16, gload_lds dbuf, swizzled LDS, XCD swizzle.
// CM: 0=f32 row-major, 1=bf16 [bh][s][64], 2=bf16 [bh][64][s],
//     3=CM1 scaled (Q), 4=CM2 with mask-zeroing (V)
template<int CM>
__global__ __launch_bounds__(256) void gemm3(const short* __restrict__ A, const short* __restrict__ Bt,
                                             void* __restrict__ Cp, int M, int N, int K,
                                             const int* __restrict__ mask) {
  __shared__ __align__(16) short Al[2][128 * 64];
  __shared__ __align__(16) short Bl[2][64 * 64];
  const int tid = threadIdx.x;
  const int lane = tid & 63, w = tid >> 6;
  const int wm = w >> 1, wn = w & 1;
  const int lr = lane & 15, g = lane >> 4;

  const int flat = blockIdx.y * gridDim.x + blockIdx.x;
  const int nwg = gridDim.x * gridDim.y;
  const int wid = (flat & 7) * (nwg >> 3) + (flat >> 3);
  const int bx = wid % gridDim.x, by = wid / gridDim.x;
  const int m0 = by * 128, n0 = bx * 64;

  f32x4 acc[4][2];
#pragma unroll
  for (int i = 0; i < 4; i++)
#pragma unroll
    for (int j = 0; j < 2; j++) acc[i][j] = (f32x4){0.f, 0.f, 0.f, 0.f};

  const int srow = lane >> 3;
  const int sch = (lane & 7) ^ (srow & 7);
  const short* gA = A + (size_t)(m0 + w * 32 + srow) * K + 8 * sch;
  const short* gB = Bt + (size_t)(n0 + w * 16 + srow) * K + 8 * sch;

#define STAGE(buf, kk)                                                              \
  do {                                                                              \
    _Pragma("unroll") for (int c = 0; c < 4; c++)                                   \
        gload16(gA + (size_t)c * 8 * K + (kk), &Al[buf][(w * 32 + c * 8) * 64]);    \
    _Pragma("unroll") for (int c = 0; c < 2; c++)                                   \
        gload16(gB + (size_t)c * 8 * K + (kk), &Bl[buf][(w * 16 + c * 8) * 64]);    \
  } while (0)

  const int nsteps = K >> 6;
  STAGE(0, 0);
  int buf = 0;
  for (int t = 0; t < nsteps; t++) {
    __syncthreads();
    if (t + 1 < nsteps) STAGE(buf ^ 1, (t + 1) << 6);
#pragma unroll
    for (int kc = 0; kc < 2; kc++) {
      bf16x8 af[4], bfr[2];
#pragma unroll
      for (int mt = 0; mt < 4; mt++) {
        int row = wm * 64 + mt * 16 + lr;
        af[mt] = *(const bf16x8*)&Al[buf][row * 64 + 8 * ((kc * 4 + g) ^ (lr & 7))];
      }
#pragma unroll
      for (int nt = 0; nt < 2; nt++) {
        int row = wn * 32 + nt * 16 + lr;
        bfr[nt] = *(const bf16x8*)&Bl[buf][row * 64 + 8 * ((kc * 4 + g) ^ (lr & 7))];
      }
      __builtin_amdgcn_s_setprio(1);
#pragma unroll
      for (int mt = 0; mt < 4; mt++)
#pragma unroll
        for (int nt = 0; nt < 2; nt++)
          acc[mt][nt] = __builtin_amdgcn_mfma_f32_16x16x32_bf16(af[mt], bfr[nt], acc[mt][nt], 0, 0, 0);
      __builtin_amdgcn_s_setprio(0);
    }
    buf ^= 1;
  }
#undef STAGE

#pragma unroll
  for (int mt = 0; mt < 4; mt++)
#pragma unroll
    for (int nt = 0; nt < 2; nt++) {
      if (CM == 0) {
#pragma unroll
        for (int r = 0; r < 4; r++) {
          int row = m0 + wm * 64 + mt * 16 + g * 4 + r;
          int col = n0 + wn * 32 + nt * 16 + lr;
          ((float*)Cp)[(size_t)row * N + col] = acc[mt][nt][r];
        }
      } else if (CM == 1 || CM == 3) {
        const float scale = (CM == 3) ? 0.18033688011f : 1.f;
#pragma unroll
        for (int r = 0; r < 4; r++) {
          int row = m0 + wm * 64 + mt * 16 + g * 4 + r;
          int col = n0 + wn * 32 + nt * 16 + lr;
          int b = row >> 11, s = row & (S_LEN - 1);
          int h = col >> 6, d = col & 63;
          ((short*)Cp)[(((size_t)(b * NHEAD + h)) * S_LEN + s) * 64 + d] = f2bf(acc[mt][nt][r] * scale);
        }
      } else {
#pragma unroll
        for (int r = 0; r < 4; r++) {
          int row = m0 + wm * 64 + mt * 16 + g * 4 + r;
          int col = n0 + wn * 32 + nt * 16 + lr;
          int h = row >> 6, d = row & 63;
          int b = col >> 11, s = col & (S_LEN - 1);
          float v = acc[mt][nt][r];
          if (CM == 4) v = mask[b * S_LEN + s] ? v : 0.f;
          ((short*)Cp)[(((size_t)(b * NHEAD + h)) * 64 + d) * S_LEN + s] = f2bf(v);
        }
      }
    }
}

// ---------------- gemm2 (fallback small-ws path)
template<int AM, int BMODE, int CM>
__global__ __launch_bounds__(256) void gemm2(const void* __restrict__ Ap, const void* __restrict__ Bp,
                                             void* __restrict__ Cp, int M, int N, int K) {
  __shared__ __align__(16) short Al[128][72];
  __shared__ __align__(16) short Bl[64][72];
  const int tid = threadIdx.x;
  const int lane = tid & 63, w = tid >> 6;
  const int wm = w >> 1, wn = w & 1;
  const int lr = lane & 15, g = lane >> 4;
  const int m0 = blockIdx.y * 128, n0 = blockIdx.x * 64;

  f32x4 acc[4][2];
#pragma unroll
  for (int i = 0; i < 4; i++)
#pragma unroll
    for (int j = 0; j < 2; j++) acc[i][j] = (f32x4){0.f, 0.f, 0.f, 0.f};

  const int ar = tid >> 1, ac = (tid & 1) * 32;
  const int br = tid >> 2, bc = (tid & 3) * 16;

  float4 la[8]; bf16x8 la8[4];
  float4 lb[4]; bf16x8 lb8[2];

#define LOADA(kk)                                                                        \
  do {                                                                                   \
    if (AM == 0) {                                                                       \
      const float* A = (const float*)Ap;                                                 \
      _Pragma("unroll") for (int j = 0; j < 8; j++)                                      \
          la[j] = *(const float4*)&A[(size_t)(m0 + ar) * K + (kk) + ac + 4 * j];         \
    } else {                                                                             \
      const short* A = (const short*)Ap;                                                 \
      _Pragma("unroll") for (int j = 0; j < 4; j++)                                      \
          la8[j] = *(const bf16x8*)&A[(size_t)(m0 + ar) * K + (kk) + ac + 8 * j];        \
    }                                                                                    \
  } while (0)

#define LOADB(kk)                                                                        \
  do {                                                                                   \
    if (BMODE == 0) {                                                                    \
      const float* B = (const float*)Bp;                                                 \
      _Pragma("unroll") for (int j = 0; j < 4; j++)                                      \
          lb[j] = *(const float4*)&B[(size_t)(n0 + br) * K + (kk) + bc + 4 * j];         \
    } else if (BMODE == 1) {                                                             \
      const short* B = (const short*)Bp;                                                 \
      _Pragma("unroll") for (int j = 0; j < 2; j++)                                      \
          lb8[j] = *(const bf16x8*)&B[(size_t)(n0 + br) * K + (kk) + bc + 8 * j];        \
    } else {                                                                             \
      const float* B = (const float*)Bp;                                                 \
      _Pragma("unroll") for (int j = 0; j < 4; j++)                                      \
          lb[j] = *(const float4*)&B[(size_t)((kk) + br) * N + n0 + bc + 4 * j];         \
    }                                                                                    \
  } while (0)

  const int nsteps = K >> 6;
  LOADA(0); LOADB(0);

  for (int t = 0; t < nsteps; t++) {
    __syncthreads();
    if (AM == 0) {
#pragma unroll
      for (int j = 0; j < 4; j++) {
        float4 v0 = la[2 * j], v1 = la[2 * j + 1];
        bf16x8 tt;
        tt[0] = f2bf(v0.x); tt[1] = f2bf(v0.y); tt[2] = f2bf(v0.z); tt[3] = f2bf(v0.w);
        tt[4] = f2bf(v1.x); tt[5] = f2bf(v1.y); tt[6] = f2bf(v1.z); tt[7] = f2bf(v1.w);
        *(bf16x8*)&Al[ar][ac + 8 * j] = tt;
      }
    } else {
#pragma unroll
      for (int j = 0; j < 4; j++) *(bf16x8*)&Al[ar][ac + 8 * j] = la8[j];
    }
    if (BMODE == 0) {
#pragma unroll
      for (int j = 0; j < 2; j++) {
        float4 v0 = lb[2 * j], v1 = lb[2 * j + 1];
        bf16x8 tt;
        tt[0] = f2bf(v0.x); tt[1] = f2bf(v0.y); tt[2] = f2bf(v0.z); tt[3] = f2bf(v0.w);
        tt[4] = f2bf(v1.x); tt[5] = f2bf(v1.y); tt[6] = f2bf(v1.z); tt[7] = f2bf(v1.w);
        *(bf16x8*)&Bl[br][bc + 8 * j] = tt;
      }
    } else if (BMODE == 1) {
#pragma unroll
      for (int j = 0; j < 2; j++) *(bf16x8*)&Bl[br][bc + 8 * j] = lb8[j];
    } else {
#pragma unroll
      for (int j = 0; j < 4; j++) {
        float4 v = lb[j];
        Bl[bc + 4 * j + 0][br] = f2bf(v.x);
        Bl[bc + 4 * j + 1][br] = f2bf(v.y);
        Bl[bc + 4 * j + 2][br] = f2bf(v.z);
        Bl[bc + 4 * j + 3][br] = f2bf(v.w);
      }
    }
    __syncthreads();
    if (t + 1 < nsteps) { LOADA((t + 1) << 6); LOADB((t + 1) << 6); }
#pragma unroll
    for (int kc = 0; kc < 2; kc++) {
      bf16x8 af[4], bfr[2];
#pragma unroll
      for (int mt = 0; mt < 4; mt++) af[mt] = *(const bf16x8*)&Al[wm * 64 + mt * 16 + lr][kc * 32 + g * 8];
#pragma unroll
      for (int nt = 0; nt < 2; nt++) bfr[nt] = *(const bf16x8*)&Bl[wn * 32 + nt * 16 + lr][kc * 32 + g * 8];
#pragma unroll
      for (int mt = 0; mt < 4; mt++)
#pragma unroll
        for (int nt = 0; nt < 2; nt++)
          acc[mt][nt] = __builtin_amdgcn_mfma_f32_16x16x32_bf16(af[mt], bfr[nt], acc[mt][nt], 0, 0, 0);
    }
  }
#undef LOADA
#undef LOADB

#pragma unroll
  for (int mt = 0; mt < 4; mt++)
#pragma unroll
    for (int nt = 0; nt < 2; nt++)
#pragma unroll
      for (int r = 0; r < 4; r++) {
        int row = m0 + wm * 64 + mt * 16 + g * 4 + r;
        int col = n0 + wn * 32 + nt * 16 + lr;
        if (CM == 0) {
          ((float*)Cp)[(size_t)row * N + col] = acc[mt][nt][r];
        } else if (CM == 1 || CM == 3) {
          float v = (CM == 3) ? acc[mt][nt][r] * 0.18033688011f : acc[mt][nt][r];
          int b = row >> 11, s = row & (S_LEN - 1);
          int h = col >> 6, d = col & 63;
          ((short*)Cp)[(((size_t)(b * NHEAD + h)) * S_LEN + s) * 64 + d] = f2bf(v);
        } else {
          int h = row >> 6, d = row & 63;
          int b = col >> 11, s = col & (S_LEN - 1);
          ((short*)Cp)[(((size_t)(b * NHEAD + h)) * 64 + d) * S_LEN + s] = f2bf(acc[mt][nt][r]);
        }
      }
}

// ---------------- attn9: QBLK=256 (4 waves x 64 q), KV-SPLIT 2 -> 512 blocks
// (2/CU). Each block does half the keys; partial O,l merged via f32 atomicAdd
// (2 adds per element = bit-deterministic). Mask-free inner loop (V pre-zeroed,
// lsum via MFMA vs Mb). Q pre-scaled 0.125*log2e; exp2 softmax, max-free.
__global__ __launch_bounds__(256, 2) void attn9(const short* __restrict__ Qb,
                                                const short* __restrict__ Kb,
                                                const short* __restrict__ VbT,
                                                const short* __restrict__ Mb,
                                                float* __restrict__ op0, float* __restrict__ op1,
                                                float* __restrict__ op2, float* __restrict__ Lp) {
  __shared__ __align__(16) short Kl[2][64][64];
  __shared__ __align__(16) short Vl[2][64][64];

  const int tid = threadIdx.x;
  const int lane = tid & 63, w = tid >> 6;  // 4 waves
  const int lr = lane & 15, g = lane >> 4;

  // 512 blocks, XCD-chunked: per XCD 64 wids = 4 heads x 2 halves x 8 qblks
  const int flat = blockIdx.y * gridDim.x + blockIdx.x;
  const int wid = (flat & 7) * 64 + (flat >> 3);
  const int qblk = wid & 7, half = (wid >> 3) & 1, bh = wid >> 4;
  const int b = bh >> 4, h = bh & 15;
  const int qbase = qblk * 256;
  const int kb0 = half * 1024;
  const size_t hoff = (size_t)bh * S_LEN * 64;

  // Q frags: 64 q-rows per wave (4 x 16), 64 d (2 halves)
  bf16x8 qf[4][2];
#pragma unroll
  for (int qfr = 0; qfr < 4; qfr++)
#pragma unroll
    for (int kh = 0; kh < 2; kh++)
      qf[qfr][kh] = *(const bf16x8*)&Qb[hoff + (size_t)(qbase + w * 64 + qfr * 16 + lr) * 64 + kh * 32 + g * 8];

  f32x4 o_acc[4][4];
  f32x4 o_l[4];
#pragma unroll
  for (int qfr = 0; qfr < 4; qfr++) {
    o_l[qfr] = (f32x4){0.f, 0.f, 0.f, 0.f};
#pragma unroll
    for (int dg = 0; dg < 4; dg++) o_acc[qfr][dg] = (f32x4){0.f, 0.f, 0.f, 0.f};
  }

  const short* Mbb = Mb + b * S_LEN;
  const int srow = lane >> 3;
  const int sch = (lane & 7) ^ (srow & 7);
  const short* gK = Kb + hoff + (size_t)(w * 16 + srow) * 64 + 8 * sch;
  const short* gV = VbT + hoff + (size_t)(w * 16 + srow) * S_LEN + 8 * sch;

#define STAGEKV(buf, kb)                                                         \
  do {                                                                           \
    _Pragma("unroll") for (int c = 0; c < 2; c++)                                \
        gload16(gK + (size_t)(kb + c * 8) * 64, &Kl[buf][w * 16 + c * 8][0]);    \
    _Pragma("unroll") for (int c = 0; c < 2; c++)                                \
        gload16(gV + (size_t)c * 8 * S_LEN + (kb), &Vl[buf][w * 16 + c * 8][0]); \
  } while (0)

  const int NT = 1024 / 64;  // 16 tiles per half
  STAGEKV(0, kb0);
  int buf = 0;

  for (int t = 0; t < NT; t++) {
    const int kb = kb0 + t * 64;
    bf16x8 mf0 = *(const bf16x8*)&Mbb[kb + g * 8];
    bf16x8 mf1 = *(const bf16x8*)&Mbb[kb + 32 + g * 8];
    __syncthreads();  // vmcnt drained: tile t resident; prior reads of buf^1 done
    if (t + 1 < NT) STAGEKV(buf ^ 1, kb + 64);

    // K / V frags, shared across the 4 q-frags
    bf16x8 kfr[4][2], vfr[4][2];
#pragma unroll
    for (int nt = 0; nt < 4; nt++)
#pragma unroll
      for (int kh = 0; kh < 2; kh++)
        kfr[nt][kh] = *(const bf16x8*)&Kl[buf][nt * 16 + lr][8 * ((4 * kh + g) ^ (lr & 7))];
#pragma unroll
    for (int dg = 0; dg < 4; dg++)
#pragma unroll
      for (int kh = 0; kh < 2; kh++)
        vfr[dg][kh] = *(const bf16x8*)&Vl[buf][dg * 16 + lr][8 * ((4 * kh + g) ^ (lr & 7))];

#pragma unroll
    for (int qfr = 0; qfr < 4; qfr++) {
      // swapped QK^T: lane holds P[q=lr][k = nt*16 + 4g + r]
      f32x4 s[4];
#pragma unroll
      for (int nt = 0; nt < 4; nt++) s[nt] = (f32x4){0.f, 0.f, 0.f, 0.f};
      __builtin_amdgcn_s_setprio(1);
#pragma unroll
      for (int nt = 0; nt < 4; nt++) {
        s[nt] = __builtin_amdgcn_mfma_f32_16x16x32_bf16(kfr[nt][0], qf[qfr][0], s[nt], 0, 0, 0);
        s[nt] = __builtin_amdgcn_mfma_f32_16x16x32_bf16(kfr[nt][1], qf[qfr][1], s[nt], 0, 0, 0);
      }
      __builtin_amdgcn_s_setprio(0);

      unsigned W0[4], W1[4];
#pragma unroll
      for (int nt = 0; nt < 4; nt++) {
        float p0 = EXP2(s[nt][0]);
        float p1 = EXP2(s[nt][1]);
        float p2 = EXP2(s[nt][2]);
        float p3 = EXP2(s[nt][3]);
        W0[nt] = cvt_pk_bf16(p0, p1);
        W1[nt] = cvt_pk_bf16(p2, p3);
      }

      bf16x8 pf[2];
#pragma unroll
      for (int kh = 0; kh < 2; kh++) {
        unsigned a0 = W0[2 * kh], b0 = W0[2 * kh + 1];
        unsigned a1 = W1[2 * kh], b1 = W1[2 * kh + 1];
        pl32swap(a0, b0); pl16swap(a0, b0);
        pl32swap(a1, b1); pl16swap(a1, b1);
        union { unsigned u[4]; bf16x8 v; } pk;
        pk.u[0] = a0; pk.u[1] = a1; pk.u[2] = b0; pk.u[3] = b1;
        pf[kh] = pk.v;
      }

      __builtin_amdgcn_s_setprio(1);
#pragma unroll
      for (int dg = 0; dg < 4; dg++) {
        o_acc[qfr][dg] = __builtin_amdgcn_mfma_f32_16x16x32_bf16(pf[0], vfr[dg][0], o_acc[qfr][dg], 0, 0, 0);
        o_acc[qfr][dg] = __builtin_amdgcn_mfma_f32_16x16x32_bf16(pf[1], vfr[dg][1], o_acc[qfr][dg], 0, 0, 0);
      }
      o_l[qfr] = __builtin_amdgcn_mfma_f32_16x16x32_bf16(pf[0], mf0, o_l[qfr], 0, 0, 0);
      o_l[qfr] = __builtin_amdgcn_mfma_f32_16x16x32_bf16(pf[1], mf1, o_l[qfr], 0, 0, 0);
      __builtin_amdgcn_s_setprio(0);
    }
    buf ^= 1;
  }
#undef STAGEKV

  // ---- epilogue: atomic-merge partial O and l (2 halves -> deterministic)
#pragma unroll
  for (int qfr = 0; qfr < 4; qfr++)
#pragma unroll
    for (int r = 0; r < 4; r++) {
      int qr = qbase + w * 64 + qfr * 16 + 4 * g + r;
      int tok = b * S_LEN + qr;
      float* row = op_row(op0, op1, op2, tok);
#pragma unroll
      for (int dg = 0; dg < 4; dg++)
        atomicAdd(&row[h * 64 + dg * 16 + lr], o_acc[qfr][dg][r]);
      if (lr == 0) atomicAdd(&Lp[(size_t)(b * NHEAD + h) * S_LEN + qr], o_l[qfr][r]);
    }
}

// ---------------- gemmM: out = diag(1/l) * O_unnorm @ Wo, merge folded into
// A-stage (reads f32 partial-O pieces + L, scales, converts to bf16).
// BM=128 BN=64 BK=64; A reg-staged (single Al), B gload16 dbuf.
__global__ __launch_bounds__(256) void gemmM(float* __restrict__ op0, float* __restrict__ op1,
                                             float* __restrict__ op2, const float* __restrict__ Lp,
                                             const short* __restrict__ WoT, float* __restrict__ out) {
  __shared__ __align__(16) short Al[128 * 64];
  __shared__ __align__(16) short Bl[2][64 * 64];
  const int tid = threadIdx.x;
  const int lane = tid & 63, w = tid >> 6;
  const int wm = w >> 1, wn = w & 1;
  const int lr = lane & 15, g = lane >> 4;

  // grid (16,32) = 512, XCD-chunked
  const int flat = blockIdx.y * gridDim.x + blockIdx.x;
  const int wid = (flat & 7) * 64 + (flat >> 3);
  const int bx = wid & 15, by = wid >> 4;
  const int m0 = by * 128, n0 = bx * 64;

  f32x4 acc[4][2];
#pragma unroll
  for (int i = 0; i < 4; i++)
#pragma unroll
    for (int j = 0; j < 2; j++) acc[i][j] = (f32x4){0.f, 0.f, 0.f, 0.f};

  const int ar = tid >> 1, ac = (tid & 1) * 32;
  const int tok = m0 + ar;
  const float* arow = op_row(op0, op1, op2, tok);
  const int b = tok >> 11, s = tok & (S_LEN - 1);

  const int srow = lane >> 3;
  const int sch = (lane & 7) ^ (srow & 7);
  const short* gB = WoT + (size_t)(n0 + w * 16 + srow) * 1024 + 8 * sch;

  float4 la[8];
  float lv;
#define LOADA(kk)                                                             \
  do {                                                                        \
    _Pragma("unroll") for (int j = 0; j < 8; j++)                             \
        la[j] = *(const float4*)&arow[(kk) + ac + 4 * j];                     \
    lv = Lp[(size_t)(b * NHEAD + ((kk) >> 6)) * S_LEN + s];                   \
  } while (0)
#define STAGEB(buf, kk)                                                             \
  do {                                                                              \
    _Pragma("unroll") for (int c = 0; c < 2; c++)                                   \
        gload16(gB + (size_t)c * 8 * 1024 + (kk), &Bl[buf][(w * 16 + c * 8) * 64]); \
  } while (0)

  const int nsteps = 16;
  LOADA(0);
  STAGEB(0, 0);
  int buf = 0;
  for (int t = 0; t < nsteps; t++) {
    __syncthreads();  // Bl[buf] resident; prev compute done
    const float inv = 1.f / lv;
#pragma unroll
    for (int j = 0; j < 4; j++) {
      float4 v0 = la[2 * j], v1 = la[2 * j + 1];
      bf16x8 tt;
      tt[0] = f2bf(v0.x * inv); tt[1] = f2bf(v0.y * inv);
      tt[2] = f2bf(v0.z * inv); tt[3] = f2bf(v0.w * inv);
      tt[4] = f2bf(v1.x * inv); tt[5] = f2bf(v1.y * inv);
      tt[6] = f2bf(v1.z * inv); tt[7] = f2bf(v1.w * inv);
      *(bf16x8*)&Al[ar * 64 + 8 * (((ac >> 3) + j) ^ (ar & 7))] = tt;
    }
    __syncthreads();  // Al visible
    if (t + 1 < nsteps) { STAGEB(buf ^ 1, (t + 1) << 6); LOADA((t + 1) << 6); }
#pragma unroll
    for (int kc = 0; kc < 2; kc++) {
      bf16x8 af[4], bfr[2];
#pragma unroll
      for (int mt = 0; mt < 4; mt++) {
        int row = wm * 64 + mt * 16 + lr;
        af[mt] = *(const bf16x8*)&Al[row * 64 + 8 * ((kc * 4 + g) ^ (lr & 7))];
      }
#pragma unroll
      for (int nt = 0; nt < 2; nt++) {
        int row = wn * 32 + nt * 16 + lr;
        bfr[nt] = *(const bf16x8*)&Bl[buf][row * 64 + 8 * ((kc * 4 + g) ^ (lr & 7))];
      }
      __builtin_amdgcn_s_setprio(1);
#pragma unroll
      for (int mt = 0; mt < 4; mt++)
#pragma unroll
        for (int nt = 0; nt < 2; nt++)
          acc[mt][nt] = __builtin_amdgcn_mfma_f32_16x16x32_bf16(af[mt], bfr[nt], acc[mt][nt], 0, 0, 0);
      __builtin_amdgcn_s_setprio(0);
    }
    buf ^= 1;
  }
#undef LOADA
#undef STAGEB

#pragma unroll
  for (int mt = 0; mt < 4; mt++)
#pragma unroll
    for (int nt = 0; nt < 2; nt++)
#pragma unroll
      for (int r = 0; r < 4; r++) {
        int row = m0 + wm * 64 + mt * 16 + g * 4 + r;
        int col = n0 + wn * 32 + nt * 16 + lr;
        out[(size_t)row * DM + col] = acc[mt][nt][r];
      }
}

// ---------------- attn8 (middle tier, round-10 proven)
__global__ __launch_bounds__(256, 4) void attn8(const short* __restrict__ Qb,
                                                const short* __restrict__ Kb,
                                                const short* __restrict__ VbT,
                                                const short* __restrict__ Mb,
                                                short* __restrict__ Ob) {
  __shared__ __align__(16) short Kl[2][64][64];
  __shared__ __align__(16) short Vl[2][64][64];

  const int tid = threadIdx.x;
  const int lane = tid & 63, w = tid >> 6;
  const int lr = lane & 15, g = lane >> 4;

  const int flat = blockIdx.y * gridDim.x + blockIdx.x;
  const int wid = (flat & 7) * 128 + (flat >> 3);
  const int qblk = wid & 31, bh = wid >> 5;
  const int b = bh >> 4, h = bh & 15;
  const int qbase = qblk * 64;
  const size_t hoff = (size_t)bh * S_LEN * 64;

  bf16x8 qf[2];
#pragma unroll
  for (int kh = 0; kh < 2; kh++)
    qf[kh] = *(const bf16x8*)&Qb[hoff + (size_t)(qbase + w * 16 + lr) * 64 + kh * 32 + g * 8];

  f32x4 o_acc[4];
  f32x4 o_l = (f32x4){0.f, 0.f, 0.f, 0.f};
#pragma unroll
  for (int dg = 0; dg < 4; dg++) o_acc[dg] = (f32x4){0.f, 0.f, 0.f, 0.f};

  const short* Mbb = Mb + b * S_LEN;
  const int srow = lane >> 3;
  const int sch = (lane & 7) ^ (srow & 7);
  const short* gK = Kb + hoff + (size_t)(w * 16 + srow) * 64 + 8 * sch;
  const short* gV = VbT + hoff + (size_t)(w * 16 + srow) * S_LEN + 8 * sch;

#define STAGEKV(buf, kb)                                                         \
  do {                                                                           \
    _Pragma("unroll") for (int c = 0; c < 2; c++)                                \
        gload16(gK + (size_t)(kb + c * 8) * 64, &Kl[buf][w * 16 + c * 8][0]);    \
    _Pragma("unroll") for (int c = 0; c < 2; c++)                                \
        gload16(gV + (size_t)c * 8 * S_LEN + (kb), &Vl[buf][w * 16 + c * 8][0]); \
  } while (0)

  const int NT = S_LEN / 64;
  STAGEKV(0, 0);
  int buf = 0;

  for (int t = 0; t < NT; t++) {
    const int kb = t * 64;
    bf16x8 mf0 = *(const bf16x8*)&Mbb[kb + g * 8];
    bf16x8 mf1 = *(const bf16x8*)&Mbb[kb + 32 + g * 8];
    __syncthreads();
    if (t + 1 < NT) STAGEKV(buf ^ 1, kb + 64);

    f32x4 s[4];
#pragma unroll
    for (int nt = 0; nt < 4; nt++) s[nt] = (f32x4){0.f, 0.f, 0.f, 0.f};
    __builtin_amdgcn_s_setprio(1);
#pragma unroll
    for (int nt = 0; nt < 4; nt++) {
      bf16x8 k0 = *(const bf16x8*)&Kl[buf][nt * 16 + lr][8 * (g ^ (lr & 7))];
      bf16x8 k1 = *(const bf16x8*)&Kl[buf][nt * 16 + lr][8 * ((4 + g) ^ (lr & 7))];
      s[nt] = __builtin_amdgcn_mfma_f32_16x16x32_bf16(k0, qf[0], s[nt], 0, 0, 0);
      s[nt] = __builtin_amdgcn_mfma_f32_16x16x32_bf16(k1, qf[1], s[nt], 0, 0, 0);
    }
    __builtin_amdgcn_s_setprio(0);

    unsigned W0[4], W1[4];
#pragma unroll
    for (int nt = 0; nt < 4; nt++) {
      float p0 = EXP2(s[nt][0]);
      float p1 = EXP2(s[nt][1]);
      float p2 = EXP2(s[nt][2]);
      float p3 = EXP2(s[nt][3]);
      W0[nt] = cvt_pk_bf16(p0, p1);
      W1[nt] = cvt_pk_bf16(p2, p3);
    }

    bf16x8 pf[2];
#pragma unroll
    for (int kh = 0; kh < 2; kh++) {
      unsigned a0 = W0[2 * kh], b0 = W0[2 * kh + 1];
      unsigned a1 = W1[2 * kh], b1 = W1[2 * kh + 1];
      pl32swap(a0, b0); pl16swap(a0, b0);
      pl32swap(a1, b1); pl16swap(a1, b1);
      union { unsigned u[4]; bf16x8 v; } pk;
      pk.u[0] = a0; pk.u[1] = a1; pk.u[2] = b0; pk.u[3] = b1;
      pf[kh] = pk.v;
    }

    __builtin_amdgcn_s_setprio(1);
#pragma unroll
    for (int dg = 0; dg < 4; dg++) {
      bf16x8 v0 = *(const bf16x8*)&Vl[buf][dg * 16 + lr][8 * (g ^ (lr & 7))];
      bf16x8 v1 = *(const bf16x8*)&Vl[buf][dg * 16 + lr][8 * ((4 + g) ^ (lr & 7))];
      o_acc[dg] = __builtin_amdgcn_mfma_f32_16x16x32_bf16(pf[0], v0, o_acc[dg], 0, 0, 0);
      o_acc[dg] = __builtin_amdgcn_mfma_f32_16x16x32_bf16(pf[1], v1, o_acc[dg], 0, 0, 0);
    }
    o_l = __builtin_amdgcn_mfma_f32_16x16x32_bf16(pf[0], mf0, o_l, 0, 0, 0);
    o_l = __builtin_amdgcn_mfma_f32_16x16x32_bf16(pf[1], mf1, o_l, 0, 0, 0);
    __builtin_amdgcn_s_setprio(0);
    buf ^= 1;
  }
#undef STAGEKV

#pragma unroll
  for (int r = 0; r < 4; r++) {
    float inv = 1.f / o_l[r];
    int qr = qbase + w * 16 + 4 * g + r;
#pragma unroll
    for (int dg = 0; dg < 4; dg++) {
      int col = h * 64 + dg * 16 + lr;
      Ob[((size_t)b * S_LEN + qr) * DM + col] = f2bf(o_acc[dg][r] * inv);
    }
  }
}

// ---------------- attn7 (small-ws fallback, self-masking)
__global__ __launch_bounds__(256, 4) void attn7(const short* __restrict__ Qb,
                                                const short* __restrict__ Kb,
                                                const short* __restrict__ VbT,
                                                const int* __restrict__ mask,
                                                short* __restrict__ Ob) {
  __shared__ __align__(16) short Kl[2][64][64];
  __shared__ __align__(16) short Vl[2][64][64];

  const int tid = threadIdx.x;
  const int lane = tid & 63, w = tid >> 6;
  const int lr = lane & 15, g = lane >> 4;

  const int flat = blockIdx.y * gridDim.x + blockIdx.x;
  const int wid = (flat & 7) * 128 + (flat >> 3);
  const int qblk = wid & 31, bh = wid >> 5;
  const int b = bh >> 4, h = bh & 15;
  const int qbase = qblk * 64;
  const size_t hoff = (size_t)bh * S_LEN * 64;

  bf16x8 qf[2];
#pragma unroll
  for (int kh = 0; kh < 2; kh++)
    qf[kh] = *(const bf16x8*)&Qb[hoff + (size_t)(qbase + w * 16 + lr) * 64 + kh * 32 + g * 8];

  f32x4 o_acc[4];
  float lsum = 0.f;
#pragma unroll
  for (int dg = 0; dg < 4; dg++) o_acc[dg] = (f32x4){0.f, 0.f, 0.f, 0.f};

  const int* maskb = mask + b * S_LEN;
  const int srow = lane >> 3;
  const int sch = (lane & 7) ^ (srow & 7);
  const short* gK = Kb + hoff + (size_t)(w * 16 + srow) * 64 + 8 * sch;
  const short* gV = VbT + hoff + (size_t)(w * 16 + srow) * S_LEN + 8 * sch;

#define STAGEKV(buf, kb)                                                         \
  do {                                                                           \
    _Pragma("unroll") for (int c = 0; c < 2; c++)                                \
        gload16(gK + (size_t)(kb + c * 8) * 64, &Kl[buf][w * 16 + c * 8][0]);    \
    _Pragma("unroll") for (int c = 0; c < 2; c++)                                \
        gload16(gV + (size_t)c * 8 * S_LEN + (kb), &Vl[buf][w * 16 + c * 8][0]); \
  } while (0)

  const int NT = S_LEN / 64;
  STAGEKV(0, 0);
  int buf = 0;

  for (int t = 0; t < NT; t++) {
    const int kb = t * 64;
    __syncthreads();
    if (t + 1 < NT) STAGEKV(buf ^ 1, kb + 64);

    float bias[4][4];
#pragma unroll
    for (int nt = 0; nt < 4; nt++) {
      int4 mv = *(const int4*)&maskb[kb + nt * 16 + 4 * g];
      bias[nt][0] = mv.x ? 0.f : -1e30f;
      bias[nt][1] = mv.y ? 0.f : -1e30f;
      bias[nt][2] = mv.z ? 0.f : -1e30f;
      bias[nt][3] = mv.w ? 0.f : -1e30f;
    }

    f32x4 s[4];
#pragma unroll
    for (int nt = 0; nt < 4; nt++) s[nt] = (f32x4){0.f, 0.f, 0.f, 0.f};
    __builtin_amdgcn_s_setprio(1);
#pragma unroll
    for (int nt = 0; nt < 4; nt++) {
      bf16x8 k0 = *(const bf16x8*)&Kl[buf][nt * 16 + lr][8 * (g ^ (lr & 7))];
      bf16x8 k1 = *(const bf16x8*)&Kl[buf][nt * 16 + lr][8 * ((4 + g) ^ (lr & 7))];
      s[nt] = __builtin_amdgcn_mfma_f32_16x16x32_bf16(k0, qf[0], s[nt], 0, 0, 0);
      s[nt] = __builtin_amdgcn_mfma_f32_16x16x32_bf16(k1, qf[1], s[nt], 0, 0, 0);
    }
    __builtin_amdgcn_s_setprio(0);

    unsigned W0[4], W1[4];
#pragma unroll
    for (int nt = 0; nt < 4; nt++) {
      float p0 = EXP2(s[nt][0] + bias[nt][0]);
      float p1 = EXP2(s[nt][1] + bias[nt][1]);
      float p2 = EXP2(s[nt][2] + bias[nt][2]);
      float p3 = EXP2(s[nt][3] + bias[nt][3]);
      lsum += (p0 + p1) + (p2 + p3);
      W0[nt] = cvt_pk_bf16(p0, p1);
      W1[nt] = cvt_pk_bf16(p2, p3);
    }

    bf16x8 pf[2];
#pragma unroll
    for (int kh = 0; kh < 2; kh++) {
      unsigned a0 = W0[2 * kh], b0 = W0[2 * kh + 1];
      unsigned a1 = W1[2 * kh], b1 = W1[2 * kh + 1];
      pl32swap(a0, b0); pl16swap(a0, b0);
      pl32swap(a1, b1); pl16swap(a1, b1);
      union { unsigned u[4]; bf16x8 v; } pk;
      pk.u[0] = a0; pk.u[1] = a1; pk.u[2] = b0; pk.u[3] = b1;
      pf[kh] = pk.v;
    }

    __builtin_amdgcn_s_setprio(1);
#pragma unroll
    for (int dg = 0; dg < 4; dg++) {
      bf16x8 v0 = *(const bf16x8*)&Vl[buf][dg * 16 + lr][8 * (g ^ (lr & 7))];
      bf16x8 v1 = *(const bf16x8*)&Vl[buf][dg * 16 + lr][8 * ((4 + g) ^ (lr & 7))];
      o_acc[dg] = __builtin_amdgcn_mfma_f32_16x16x32_bf16(pf[0], v0, o_acc[dg], 0, 0, 0);
      o_acc[dg] = __builtin_amdgcn_mfma_f32_16x16x32_bf16(pf[1], v1, o_acc[dg], 0, 0, 0);
    }
    __builtin_amdgcn_s_setprio(0);
    buf ^= 1;
  }
#undef STAGEKV

  {
    float l = lsum;
    l += __shfl_xor(l, 16);
    l += __shfl_xor(l, 32);
    float inv = 1.f / l;
    float invq[4];
#pragma unroll
    for (int r = 0; r < 4; r++) invq[r] = __shfl(inv, 4 * g + r);
#pragma unroll
    for (int dg = 0; dg < 4; dg++)
#pragma unroll
      for (int r = 0; r < 4; r++) {
        int qr = qbase + w * 16 + 4 * g + r;
        int col = h * 64 + dg * 16 + lr;
        Ob[((size_t)b * S_LEN + qr) * DM + col] = f2bf(o_acc[dg][r] * invq[r]);
      }
  }
}

extern "C" void kernel_launch(void* const* d_in, const int* in_sizes, int n_in,
                              void* d_out, int out_size, void* d_ws, size_t ws_size,
                              hipStream_t stream) {
  const float* query = (const float*)d_in[0];
  const float* key   = (const float*)d_in[1];
  const float* value = (const float*)d_in[2];
  const float* Wq = (const float*)d_in[3];
  const float* Wk = (const float*)d_in[4];
  const float* Wv = (const float*)d_in[5];
  const float* Wo = (const float*)d_in[6];
  const int* mask = (const int*)d_in[7];

  char* ws = (char*)d_ws;
  const size_t MB = 1 << 20;
  const bool big2 = ws_size >= 43 * MB;
  const bool big  = ws_size >= 41 * MB;

  if (big2) {
    // [0,8) xq->Kb  [8,16) xk->VbT  [16,24) xv->op0  [24,26) WoT
    // [26,28) WqT / [28,30) WkT / [30,32) WvT -> op1 after projections
    // [32,40) Qb  [40,+8KB) Mb  [40M+64K,+256K) Lp  [41,43) op2
    short* xq  = (short*)(ws);
    short* xk  = (short*)(ws + 8 * MB);
    short* xv  = (short*)(ws + 16 * MB);
    short* WoT = (short*)(ws + 24 * MB);
    short* WqT = (short*)(ws + 26 * MB);
    short* WkT = (short*)(ws + 28 * MB);
    short* WvT = (short*)(ws + 30 * MB);
    short* Qb  = (short*)(ws + 32 * MB);
    short* Mb  = (short*)(ws + 40 * MB);
    float* Lp  = (float*)(ws + 40 * MB + 64 * 1024);
    float* op0 = (float*)(ws + 16 * MB);
    float* op1 = (float*)(ws + 26 * MB);
    float* op2 = (float*)(ws + 41 * MB);
    short* Kb  = xq;
    short* VbT = xk;

    dim3 tgrid(16, 16, 5);
    wtrans<<<tgrid, 256, 0, stream>>>(Wq, Wk, Wv, Wo, mask, WqT, WkT, WvT, WoT, Mb);
    dim3 cg(1024, 3);
    xcvt<<<cg, 256, 0, stream>>>(query, key, value, xq, xk, xv);

    dim3 gqk(DM / 64, (2 * S_LEN) / 128);  // (16, 32) = 512
    gemm3<3><<<gqk, 256, 0, stream>>>(xq, WqT, Qb, 2 * S_LEN, DM, DM, mask);
    gemm3<1><<<gqk, 256, 0, stream>>>(xk, WkT, Kb, 2 * S_LEN, DM, DM, mask);
    dim3 gv((2 * S_LEN) / 64, DM / 128);   // (64, 8) = 512
    gemm3<4><<<gv, 256, 0, stream>>>(WvT, xv, VbT, DM, 2 * S_LEN, DM, mask);

    // zero partial-O pieces + L (stream-ordered after projections)
    hipMemsetAsync(op0, 0, 8 * MB, stream);
    hipMemsetAsync(op1, 0, 6 * MB, stream);
    hipMemsetAsync(op2, 0, 2 * MB, stream);
    hipMemsetAsync(Lp, 0, 2 * NHEAD * S_LEN * sizeof(float), stream);

    dim3 ag(16, 32);  // 512 blocks: 8 qblk x 2 half x 32 bh
    attn9<<<ag, 256, 0, stream>>>(Qb, Kb, VbT, Mb, op0, op1, op2, Lp);

    dim3 go(16, 32);
    gemmM<<<go, 256, 0, stream>>>(op0, op1, op2, Lp, WoT, (float*)d_out);
  } else if (big) {
    // round-10 layout (proven)
    short* xq  = (short*)(ws);
    short* xk  = (short*)(ws + 8 * MB);
    short* xv  = (short*)(ws + 16 * MB);
    short* WqT = (short*)(ws + 24 * MB);
    short* WkT = (short*)(ws + 26 * MB);
    short* WvT = (short*)(ws + 28 * MB);
    short* WoT = (short*)(ws + 30 * MB);
    short* Qb  = (short*)(ws + 32 * MB);
    short* Mb  = (short*)(ws + 40 * MB);
    short* Kb  = xq;
    short* VbT = xk;
    short* Ob  = xv;

    dim3 tgrid(16, 16, 5);
    wtrans<<<tgrid, 256, 0, stream>>>(Wq, Wk, Wv, Wo, mask, WqT, WkT, WvT, WoT, Mb);
    dim3 cg(1024, 3);
    xcvt<<<cg, 256, 0, stream>>>(query, key, value, xq, xk, xv);

    dim3 gqk(DM / 64, (2 * S_LEN) / 128);
    gemm3<3><<<gqk, 256, 0, stream>>>(xq, WqT, Qb, 2 * S_LEN, DM, DM, mask);
    gemm3<1><<<gqk, 256, 0, stream>>>(xk, WkT, Kb, 2 * S_LEN, DM, DM, mask);
    dim3 gv((2 * S_LEN) / 64, DM / 128);
    gemm3<4><<<gv, 256, 0, stream>>>(WvT, xv, VbT, DM, 2 * S_LEN, DM, mask);

    dim3 ag(S_LEN / 64, 2 * NHEAD);
    attn8<<<ag, 256, 0, stream>>>(Qb, Kb, VbT, Mb, Ob);

    gemm3<0><<<gqk, 256, 0, stream>>>(Ob, WoT, (float*)d_out, 2 * S_LEN, DM, DM, mask);
  } else {
    short* Qb  = (short*)(ws);
    short* Kb  = (short*)(ws + 8 * MB);
    short* VbT = (short*)(ws + 16 * MB);
    short* WqT = (short*)(ws + 24 * MB);
    short* WkT = (short*)(ws + 26 * MB);
    short* WvT = (short*)(ws + 28 * MB);
    short* Ob  = (short*)(ws + 24 * MB);

    dim3 tgrid(16, 16, 3);
    wtrans<<<tgrid, 256, 0, stream>>>(Wq, Wk, Wv, Wo, mask, WqT, WkT, WvT, WqT, WqT);

    dim3 gq(DM / 64, (2 * S_LEN) / 128);
    gemm2<0, 1, 3><<<gq, 256, 0, stream>>>(query, WqT, Qb, 2 * S_LEN, DM, DM);
    gemm2<0, 1, 1><<<gq, 256, 0, stream>>>(key,   WkT, Kb, 2 * S_LEN, DM, DM);
    dim3 gv((2 * S_LEN) / 64, DM / 128);
    gemm2<1, 0, 2><<<gv, 256, 0, stream>>>(WvT, value, VbT, DM, 2 * S_LEN, DM);

    dim3 ag(S_LEN / 64, 2 * NHEAD);
    attn7<<<ag, 256, 0, stream>>>(Qb, Kb, VbT, mask, Ob);

    gemm2<1, 2, 0><<<gq, 256, 0, stream>>>(Ob, Wo, (float*)d_out, 2 * S_LEN, DM, DM);
  }
}

// Round 12
// 148.380 us; speedup vs baseline: 1.2250x; 1.2250x over previous
//
#include <hip/hip_runtime.h>
#include <hip/hip_bf16.h>

typedef short bf16x8 __attribute__((ext_vector_type(8)));  // 8 bf16 (4 VGPRs)
typedef float f32x4 __attribute__((ext_vector_type(4)));

#define S_LEN 2048
#define NHEAD 16
#define DM 1024

#if __has_builtin(__builtin_amdgcn_exp2f)
#define EXP2(x) __builtin_amdgcn_exp2f(x)
#else
#define EXP2(x) exp2f(x)
#endif

__device__ __forceinline__ short f2bf(float f) {
  union { float f; unsigned u; } x; x.f = f;
  unsigned r = x.u + 0x7fffu + ((x.u >> 16) & 1u);  // RNE
  return (short)(r >> 16);
}

__device__ __forceinline__ unsigned cvt_pk_bf16(float lo, float hi) {
  unsigned r;
  asm("v_cvt_pk_bf16_f32 %0, %1, %2" : "=v"(r) : "v"(lo), "v"(hi));
  return r;
}

__device__ __forceinline__ void pl32swap(unsigned& a, unsigned& b) {
#if __has_builtin(__builtin_amdgcn_permlane32_swap)
  auto r = __builtin_amdgcn_permlane32_swap(a, b, false, false);
  a = r[0]; b = r[1];
#else
  asm volatile("v_permlane32_swap_b32 %0, %1" : "+v"(a), "+v"(b));
#endif
}
__device__ __forceinline__ void pl16swap(unsigned& a, unsigned& b) {
#if __has_builtin(__builtin_amdgcn_permlane16_swap)
  auto r = __builtin_amdgcn_permlane16_swap(a, b, false, false);
  a = r[0]; b = r[1];
#else
  asm volatile("v_permlane16_swap_b32 %0, %1" : "+v"(a), "+v"(b));
#endif
}

__device__ __forceinline__ void gload16(const void* g, void* l) {
  __builtin_amdgcn_global_load_lds(
      (const __attribute__((address_space(1))) void*)g,
      (__attribute__((address_space(3))) void*)l, 16, 0, 0);
}

// ---------------- weight transpose+convert; z==4: mask -> bf16 table Mb
__global__ __launch_bounds__(256) void wtrans(const float* __restrict__ Wq, const float* __restrict__ Wk,
                                              const float* __restrict__ Wv, const float* __restrict__ Wo,
                                              const int* __restrict__ mask,
                                              short* Tq, short* Tk, short* Tv, short* To, short* Mb) {
  const int z = blockIdx.z;
  const int tid = threadIdx.x;
  if (z == 4) {
    if (blockIdx.y == 0 && blockIdx.x < 16) {
      int i = blockIdx.x * 256 + tid;
      Mb[i] = mask[i] ? (short)0x3F80 : (short)0;  // bf16 1.0 / 0.0
    }
    return;
  }
  const float* W = (z == 0) ? Wq : (z == 1) ? Wk : (z == 2) ? Wv : Wo;
  short* T = (z == 0) ? Tq : (z == 1) ? Tk : (z == 2) ? Tv : To;
  __shared__ short Tl[64][72];
  const int k0 = blockIdx.x * 64, n0 = blockIdx.y * 64;
  const int r = tid >> 2, c0 = (tid & 3) * 16;
#pragma unroll
  for (int j = 0; j < 4; j++) {
    float4 v = *(const float4*)&W[(size_t)(k0 + r) * DM + n0 + c0 + 4 * j];
    Tl[r][c0 + 4 * j + 0] = f2bf(v.x);
    Tl[r][c0 + 4 * j + 1] = f2bf(v.y);
    Tl[r][c0 + 4 * j + 2] = f2bf(v.z);
    Tl[r][c0 + 4 * j + 3] = f2bf(v.w);
  }
  __syncthreads();
  bf16x8 o0, o1;
#pragma unroll
  for (int j = 0; j < 8; j++) { o0[j] = Tl[c0 + j][r]; o1[j] = Tl[c0 + 8 + j][r]; }
  *(bf16x8*)&T[(size_t)(n0 + r) * DM + k0 + c0] = o0;
  *(bf16x8*)&T[(size_t)(n0 + r) * DM + k0 + c0 + 8] = o1;
}

// ---------------- x f32 -> bf16 convert (3 tensors)
__global__ __launch_bounds__(256) void xcvt(const float* __restrict__ q, const float* __restrict__ k,
                                            const float* __restrict__ v,
                                            short* xq, short* xk, short* xv) {
  const int z = blockIdx.y;
  const float* src = (z == 0) ? q : (z == 1) ? k : v;
  short* dst = (z == 0) ? xq : (z == 1) ? xk : xv;
  const size_t base = ((size_t)blockIdx.x * 256 + threadIdx.x) * 16;
  float4 a = *(const float4*)&src[base];
  float4 b = *(const float4*)&src[base + 4];
  float4 c = *(const float4*)&src[base + 8];
  float4 d = *(const float4*)&src[base + 12];
  bf16x8 o0, o1;
  o0[0] = f2bf(a.x); o0[1] = f2bf(a.y); o0[2] = f2bf(a.z); o0[3] = f2bf(a.w);
  o0[4] = f2bf(b.x); o0[5] = f2bf(b.y); o0[6] = f2bf(b.z); o0[7] = f2bf(b.w);
  o1[0] = f2bf(c.x); o1[1] = f2bf(c.y); o1[2] = f2bf(c.z); o1[3] = f2bf(c.w);
  o1[4] = f2bf(d.x); o1[5] = f2bf(d.y); o1[6] = f2bf(d.z); o1[7] = f2bf(d.w);
  *(bf16x8*)&dst[base] = o0;
  *(bf16x8*)&dst[base + 8] = o1;
}

// ---------------- gemm3: all-bf16, gload_lds TRIPLE-buffer + counted vmcnt
// (T4: prefetch depth 2, vmcnt(6) per step, drain only on last step).
// CM: 0=f32 row-major, 1=bf16 [bh][s][64], 3=CM1 scaled (Q),
//     4=bf16 [bh][64][s] with mask-zeroing (V)
template<int CM>
__global__ __launch_bounds__(256) void gemm3(const short* __restrict__ A, const short* __restrict__ Bt,
                                             void* __restrict__ Cp, int M, int N, int K,
                                             const int* __restrict__ mask) {
  __shared__ __align__(16) short Al[3][128 * 64];
  __shared__ __align__(16) short Bl[3][64 * 64];
  const int tid = threadIdx.x;
  const int lane = tid & 63, w = tid >> 6;
  const int wm = w >> 1, wn = w & 1;
  const int lr = lane & 15, g = lane >> 4;

  const int flat = blockIdx.y * gridDim.x + blockIdx.x;
  const int nwg = gridDim.x * gridDim.y;
  const int wid = (flat & 7) * (nwg >> 3) + (flat >> 3);
  const int bx = wid % gridDim.x, by = wid / gridDim.x;
  const int m0 = by * 128, n0 = bx * 64;

  f32x4 acc[4][2];
#pragma unroll
  for (int i = 0; i < 4; i++)
#pragma unroll
    for (int j = 0; j < 2; j++) acc[i][j] = (f32x4){0.f, 0.f, 0.f, 0.f};

  const int srow = lane >> 3;
  const int sch = (lane & 7) ^ (srow & 7);
  const short* gA = A + (size_t)(m0 + w * 32 + srow) * K + 8 * sch;
  const short* gB = Bt + (size_t)(n0 + w * 16 + srow) * K + 8 * sch;

  // 6 gload16 per thread per stage (4 A + 2 B)
#define STAGE(buf, kk)                                                              \
  do {                                                                              \
    _Pragma("unroll") for (int c = 0; c < 4; c++)                                   \
        gload16(gA + (size_t)c * 8 * K + (kk), &Al[buf][(w * 32 + c * 8) * 64]);    \
    _Pragma("unroll") for (int c = 0; c < 2; c++)                                   \
        gload16(gB + (size_t)c * 8 * K + (kk), &Bl[buf][(w * 16 + c * 8) * 64]);    \
  } while (0)

  const int nsteps = K >> 6;
  STAGE(0, 0);
  STAGE(1, 64);
  int cur = 0, sbuf = 2;
  for (int t = 0; t < nsteps; t++) {
    if (t < nsteps - 1)
      asm volatile("s_waitcnt vmcnt(6) lgkmcnt(0)" ::: "memory");
    else
      asm volatile("s_waitcnt vmcnt(0) lgkmcnt(0)" ::: "memory");
    __builtin_amdgcn_s_barrier();
    __builtin_amdgcn_sched_barrier(0);
    if (t + 2 < nsteps) STAGE(sbuf, (t + 2) << 6);
#pragma unroll
    for (int kc = 0; kc < 2; kc++) {
      bf16x8 af[4], bfr[2];
#pragma unroll
      for (int mt = 0; mt < 4; mt++) {
        int row = wm * 64 + mt * 16 + lr;
        af[mt] = *(const bf16x8*)&Al[cur][row * 64 + 8 * ((kc * 4 + g) ^ (lr & 7))];
      }
#pragma unroll
      for (int nt = 0; nt < 2; nt++) {
        int row = wn * 32 + nt * 16 + lr;
        bfr[nt] = *(const bf16x8*)&Bl[cur][row * 64 + 8 * ((kc * 4 + g) ^ (lr & 7))];
      }
      __builtin_amdgcn_s_setprio(1);
#pragma unroll
      for (int mt = 0; mt < 4; mt++)
#pragma unroll
        for (int nt = 0; nt < 2; nt++)
          acc[mt][nt] = __builtin_amdgcn_mfma_f32_16x16x32_bf16(af[mt], bfr[nt], acc[mt][nt], 0, 0, 0);
      __builtin_amdgcn_s_setprio(0);
    }
    cur = (cur == 2) ? 0 : cur + 1;
    sbuf = (sbuf == 2) ? 0 : sbuf + 1;
  }
#undef STAGE

#pragma unroll
  for (int mt = 0; mt < 4; mt++)
#pragma unroll
    for (int nt = 0; nt < 2; nt++) {
      if (CM == 0) {
#pragma unroll
        for (int r = 0; r < 4; r++) {
          int row = m0 + wm * 64 + mt * 16 + g * 4 + r;
          int col = n0 + wn * 32 + nt * 16 + lr;
          ((float*)Cp)[(size_t)row * N + col] = acc[mt][nt][r];
        }
      } else if (CM == 1 || CM == 3) {
        const float scale = (CM == 3) ? 0.18033688011f : 1.f;
#pragma unroll
        for (int r = 0; r < 4; r++) {
          int row = m0 + wm * 64 + mt * 16 + g * 4 + r;
          int col = n0 + wn * 32 + nt * 16 + lr;
          int b = row >> 11, s = row & (S_LEN - 1);
          int h = col >> 6, d = col & 63;
          ((short*)Cp)[(((size_t)(b * NHEAD + h)) * S_LEN + s) * 64 + d] = f2bf(acc[mt][nt][r] * scale);
        }
      } else {
#pragma unroll
        for (int r = 0; r < 4; r++) {
          int row = m0 + wm * 64 + mt * 16 + g * 4 + r;
          int col = n0 + wn * 32 + nt * 16 + lr;
          int h = row >> 6, d = row & 63;
          int b = col >> 11, s = col & (S_LEN - 1);
          float v = acc[mt][nt][r];
          if (CM == 4) v = mask[b * S_LEN + s] ? v : 0.f;
          ((short*)Cp)[(((size_t)(b * NHEAD + h)) * 64 + d) * S_LEN + s] = f2bf(v);
        }
      }
    }
}

// ---------------- gemm2 (fallback small-ws path, unchanged)
template<int AM, int BMODE, int CM>
__global__ __launch_bounds__(256) void gemm2(const void* __restrict__ Ap, const void* __restrict__ Bp,
                                             void* __restrict__ Cp, int M, int N, int K) {
  __shared__ __align__(16) short Al[128][72];
  __shared__ __align__(16) short Bl[64][72];
  const int tid = threadIdx.x;
  const int lane = tid & 63, w = tid >> 6;
  const int wm = w >> 1, wn = w & 1;
  const int lr = lane & 15, g = lane >> 4;
  const int m0 = blockIdx.y * 128, n0 = blockIdx.x * 64;

  f32x4 acc[4][2];
#pragma unroll
  for (int i = 0; i < 4; i++)
#pragma unroll
    for (int j = 0; j < 2; j++) acc[i][j] = (f32x4){0.f, 0.f, 0.f, 0.f};

  const int ar = tid >> 1, ac = (tid & 1) * 32;
  const int br = tid >> 2, bc = (tid & 3) * 16;

  float4 la[8]; bf16x8 la8[4];
  float4 lb[4]; bf16x8 lb8[2];

#define LOADA(kk)                                                                        \
  do {                                                                                   \
    if (AM == 0) {                                                                       \
      const float* A = (const float*)Ap;                                                 \
      _Pragma("unroll") for (int j = 0; j < 8; j++)                                      \
          la[j] = *(const float4*)&A[(size_t)(m0 + ar) * K + (kk) + ac + 4 * j];         \
    } else {                                                                             \
      const short* A = (const short*)Ap;                                                 \
      _Pragma("unroll") for (int j = 0; j < 4; j++)                                      \
          la8[j] = *(const bf16x8*)&A[(size_t)(m0 + ar) * K + (kk) + ac + 8 * j];        \
    }                                                                                    \
  } while (0)

#define LOADB(kk)                                                                        \
  do {                                                                                   \
    if (BMODE == 0) {                                                                    \
      const float* B = (const float*)Bp;                                                 \
      _Pragma("unroll") for (int j = 0; j < 4; j++)                                      \
          lb[j] = *(const float4*)&B[(size_t)(n0 + br) * K + (kk) + bc + 4 * j];         \
    } else if (BMODE == 1) {                                                             \
      const short* B = (const short*)Bp;                                                 \
      _Pragma("unroll") for (int j = 0; j < 2; j++)                                      \
          lb8[j] = *(const bf16x8*)&B[(size_t)(n0 + br) * K + (kk) + bc + 8 * j];        \
    } else {                                                                             \
      const float* B = (const float*)Bp;                                                 \
      _Pragma("unroll") for (int j = 0; j < 4; j++)                                      \
          lb[j] = *(const float4*)&B[(size_t)((kk) + br) * N + n0 + bc + 4 * j];         \
    }                                                                                    \
  } while (0)

  const int nsteps = K >> 6;
  LOADA(0); LOADB(0);

  for (int t = 0; t < nsteps; t++) {
    __syncthreads();
    if (AM == 0) {
#pragma unroll
      for (int j = 0; j < 4; j++) {
        float4 v0 = la[2 * j], v1 = la[2 * j + 1];
        bf16x8 tt;
        tt[0] = f2bf(v0.x); tt[1] = f2bf(v0.y); tt[2] = f2bf(v0.z); tt[3] = f2bf(v0.w);
        tt[4] = f2bf(v1.x); tt[5] = f2bf(v1.y); tt[6] = f2bf(v1.z); tt[7] = f2bf(v1.w);
        *(bf16x8*)&Al[ar][ac + 8 * j] = tt;
      }
    } else {
#pragma unroll
      for (int j = 0; j < 4; j++) *(bf16x8*)&Al[ar][ac + 8 * j] = la8[j];
    }
    if (BMODE == 0) {
#pragma unroll
      for (int j = 0; j < 2; j++) {
        float4 v0 = lb[2 * j], v1 = lb[2 * j + 1];
        bf16x8 tt;
        tt[0] = f2bf(v0.x); tt[1] = f2bf(v0.y); tt[2] = f2bf(v0.z); tt[3] = f2bf(v0.w);
        tt[4] = f2bf(v1.x); tt[5] = f2bf(v1.y); tt[6] = f2bf(v1.z); tt[7] = f2bf(v1.w);
        *(bf16x8*)&Bl[br][bc + 8 * j] = tt;
      }
    } else if (BMODE == 1) {
#pragma unroll
      for (int j = 0; j < 2; j++) *(bf16x8*)&Bl[br][bc + 8 * j] = lb8[j];
    } else {
#pragma unroll
      for (int j = 0; j < 4; j++) {
        float4 v = lb[j];
        Bl[bc + 4 * j + 0][br] = f2bf(v.x);
        Bl[bc + 4 * j + 1][br] = f2bf(v.y);
        Bl[bc + 4 * j + 2][br] = f2bf(v.z);
        Bl[bc + 4 * j + 3][br] = f2bf(v.w);
      }
    }
    __syncthreads();
    if (t + 1 < nsteps) { LOADA((t + 1) << 6); LOADB((t + 1) << 6); }
#pragma unroll
    for (int kc = 0; kc < 2; kc++) {
      bf16x8 af[4], bfr[2];
#pragma unroll
      for (int mt = 0; mt < 4; mt++) af[mt] = *(const bf16x8*)&Al[wm * 64 + mt * 16 + lr][kc * 32 + g * 8];
#pragma unroll
      for (int nt = 0; nt < 2; nt++) bfr[nt] = *(const bf16x8*)&Bl[wn * 32 + nt * 16 + lr][kc * 32 + g * 8];
#pragma unroll
      for (int mt = 0; mt < 4; mt++)
#pragma unroll
        for (int nt = 0; nt < 2; nt++)
          acc[mt][nt] = __builtin_amdgcn_mfma_f32_16x16x32_bf16(af[mt], bfr[nt], acc[mt][nt], 0, 0, 0);
    }
  }
#undef LOADA
#undef LOADB

#pragma unroll
  for (int mt = 0; mt < 4; mt++)
#pragma unroll
    for (int nt = 0; nt < 2; nt++)
#pragma unroll
      for (int r = 0; r < 4; r++) {
        int row = m0 + wm * 64 + mt * 16 + g * 4 + r;
        int col = n0 + wn * 32 + nt * 16 + lr;
        if (CM == 0) {
          ((float*)Cp)[(size_t)row * N + col] = acc[mt][nt][r];
        } else if (CM == 1 || CM == 3) {
          float v = (CM == 3) ? acc[mt][nt][r] * 0.18033688011f : acc[mt][nt][r];
          int b = row >> 11, s = row & (S_LEN - 1);
          int h = col >> 6, d = col & 63;
          ((short*)Cp)[(((size_t)(b * NHEAD + h)) * S_LEN + s) * 64 + d] = f2bf(v);
        } else {
          int h = row >> 6, d = row & 63;
          int b = col >> 11, s = col & (S_LEN - 1);
          ((short*)Cp)[(((size_t)(b * NHEAD + h)) * 64 + d) * S_LEN + s] = f2bf(acc[mt][nt][r]);
        }
      }
}

// ---------------- attn10: attn8 + TRIPLE-buffered K/V, counted vmcnt(4),
// raw s_barrier (loads stay in flight across barriers), mask table in LDS
// (keeps vmcnt counting exact). QBLK=64, 4 waves, 1024 blocks.
// V rows pre-zeroed for masked keys; row-sum via MFMA vs Mb fragment.
// Q pre-scaled 0.125*log2e; exp2 softmax, max-free.
__global__ __launch_bounds__(256, 3) void attn10(const short* __restrict__ Qb,
                                                 const short* __restrict__ Kb,
                                                 const short* __restrict__ VbT,
                                                 const short* __restrict__ Mb,
                                                 short* __restrict__ Ob) {
  __shared__ __align__(16) short Kl[3][64][64];
  __shared__ __align__(16) short Vl[3][64][64];
  __shared__ __align__(16) short Ml[S_LEN];

  const int tid = threadIdx.x;
  const int lane = tid & 63, w = tid >> 6;
  const int lr = lane & 15, g = lane >> 4;

  const int flat = blockIdx.y * gridDim.x + blockIdx.x;
  const int wid = (flat & 7) * 128 + (flat >> 3);
  const int qblk = wid & 31, bh = wid >> 5;
  const int b = bh >> 4, h = bh & 15;
  const int qbase = qblk * 64;
  const size_t hoff = (size_t)bh * S_LEN * 64;

  // prologue: mask row -> LDS (one bf16x8 per thread)
  *(bf16x8*)&Ml[tid * 8] = *(const bf16x8*)&Mb[b * S_LEN + tid * 8];

  bf16x8 qf[2];
#pragma unroll
  for (int kh = 0; kh < 2; kh++)
    qf[kh] = *(const bf16x8*)&Qb[hoff + (size_t)(qbase + w * 16 + lr) * 64 + kh * 32 + g * 8];

  f32x4 o_acc[4];
  f32x4 o_l = (f32x4){0.f, 0.f, 0.f, 0.f};
#pragma unroll
  for (int dg = 0; dg < 4; dg++) o_acc[dg] = (f32x4){0.f, 0.f, 0.f, 0.f};

  const int srow = lane >> 3;
  const int sch = (lane & 7) ^ (srow & 7);
  const short* gK = Kb + hoff + (size_t)(w * 16 + srow) * 64 + 8 * sch;
  const short* gV = VbT + hoff + (size_t)(w * 16 + srow) * S_LEN + 8 * sch;

  // 4 gload16 per thread per stage (2 K + 2 V)
#define STAGEKV(buf, kb)                                                         \
  do {                                                                           \
    _Pragma("unroll") for (int c = 0; c < 2; c++)                                \
        gload16(gK + (size_t)((kb) + c * 8) * 64, &Kl[buf][w * 16 + c * 8][0]);  \
    _Pragma("unroll") for (int c = 0; c < 2; c++)                                \
        gload16(gV + (size_t)c * 8 * S_LEN + (kb), &Vl[buf][w * 16 + c * 8][0]); \
  } while (0)

  const int NT = S_LEN / 64;  // 32
  STAGEKV(0, 0);
  STAGEKV(1, 64);
  int cur = 0, sbuf = 2;

  for (int t = 0; t < NT; t++) {
    const int kb = t * 64;
    if (t < NT - 1)
      asm volatile("s_waitcnt vmcnt(4) lgkmcnt(0)" ::: "memory");
    else
      asm volatile("s_waitcnt vmcnt(0) lgkmcnt(0)" ::: "memory");
    __builtin_amdgcn_s_barrier();
    __builtin_amdgcn_sched_barrier(0);
    if (t + 2 < NT) STAGEKV(sbuf, kb + 128);

    // mask frags from LDS (B-operand layout: m[kb + kh*32 + g*8 + j])
    bf16x8 mf0 = *(const bf16x8*)&Ml[kb + g * 8];
    bf16x8 mf1 = *(const bf16x8*)&Ml[kb + 32 + g * 8];

    // ---- swapped QK^T: S^T = mfma(K, Q); lane holds P[q=lr][k=nt*16+4g+r]
    f32x4 s[4];
#pragma unroll
    for (int nt = 0; nt < 4; nt++) s[nt] = (f32x4){0.f, 0.f, 0.f, 0.f};
    __builtin_amdgcn_s_setprio(1);
#pragma unroll
    for (int nt = 0; nt < 4; nt++) {
      bf16x8 k0 = *(const bf16x8*)&Kl[cur][nt * 16 + lr][8 * (g ^ (lr & 7))];
      bf16x8 k1 = *(const bf16x8*)&Kl[cur][nt * 16 + lr][8 * ((4 + g) ^ (lr & 7))];
      s[nt] = __builtin_amdgcn_mfma_f32_16x16x32_bf16(k0, qf[0], s[nt], 0, 0, 0);
      s[nt] = __builtin_amdgcn_mfma_f32_16x16x32_bf16(k1, qf[1], s[nt], 0, 0, 0);
    }
    __builtin_amdgcn_s_setprio(0);

    // ---- softmax: p = exp2(s) (mask-free) + pack
    unsigned W0[4], W1[4];
#pragma unroll
    for (int nt = 0; nt < 4; nt++) {
      float p0 = EXP2(s[nt][0]);
      float p1 = EXP2(s[nt][1]);
      float p2 = EXP2(s[nt][2]);
      float p3 = EXP2(s[nt][3]);
      W0[nt] = cvt_pk_bf16(p0, p1);
      W1[nt] = cvt_pk_bf16(p2, p3);
    }

    // ---- in-register P redistribution to A-frag layout
    bf16x8 pf[2];
#pragma unroll
    for (int kh = 0; kh < 2; kh++) {
      unsigned a0 = W0[2 * kh], b0 = W0[2 * kh + 1];
      unsigned a1 = W1[2 * kh], b1 = W1[2 * kh + 1];
      pl32swap(a0, b0); pl16swap(a0, b0);
      pl32swap(a1, b1); pl16swap(a1, b1);
      union { unsigned u[4]; bf16x8 v; } pk;
      pk.u[0] = a0; pk.u[1] = a1; pk.u[2] = b0; pk.u[3] = b1;
      pf[kh] = pk.v;
    }

    // ---- PV (V pre-zeroed for masked k) + masked row-sum via MFMA
    __builtin_amdgcn_s_setprio(1);
#pragma unroll
    for (int dg = 0; dg < 4; dg++) {
      bf16x8 v0 = *(const bf16x8*)&Vl[cur][dg * 16 + lr][8 * (g ^ (lr & 7))];
      bf16x8 v1 = *(const bf16x8*)&Vl[cur][dg * 16 + lr][8 * ((4 + g) ^ (lr & 7))];
      o_acc[dg] = __builtin_amdgcn_mfma_f32_16x16x32_bf16(pf[0], v0, o_acc[dg], 0, 0, 0);
      o_acc[dg] = __builtin_amdgcn_mfma_f32_16x16x32_bf16(pf[1], v1, o_acc[dg], 0, 0, 0);
    }
    o_l = __builtin_amdgcn_mfma_f32_16x16x32_bf16(pf[0], mf0, o_l, 0, 0, 0);
    o_l = __builtin_amdgcn_mfma_f32_16x16x32_bf16(pf[1], mf1, o_l, 0, 0, 0);
    __builtin_amdgcn_s_setprio(0);

    cur = (cur == 2) ? 0 : cur + 1;
    sbuf = (sbuf == 2) ? 0 : sbuf + 1;
  }
#undef STAGEKV

  // ---- epilogue: o_l[r] = sum_k P[q=4g+r][k]*m[k] (per-lane correct)
#pragma unroll
  for (int r = 0; r < 4; r++) {
    float inv = 1.f / o_l[r];
    int qr = qbase + w * 16 + 4 * g + r;
#pragma unroll
    for (int dg = 0; dg < 4; dg++) {
      int col = h * 64 + dg * 16 + lr;
      Ob[((size_t)b * S_LEN + qr) * DM + col] = f2bf(o_acc[dg][r] * inv);
    }
  }
}

// ---------------- attn7 (small-ws fallback, self-masking, unchanged)
__global__ __launch_bounds__(256, 4) void attn7(const short* __restrict__ Qb,
                                                const short* __restrict__ Kb,
                                                const short* __restrict__ VbT,
                                                const int* __restrict__ mask,
                                                short* __restrict__ Ob) {
  __shared__ __align__(16) short Kl[2][64][64];
  __shared__ __align__(16) short Vl[2][64][64];

  const int tid = threadIdx.x;
  const int lane = tid & 63, w = tid >> 6;
  const int lr = lane & 15, g = lane >> 4;

  const int flat = blockIdx.y * gridDim.x + blockIdx.x;
  const int wid = (flat & 7) * 128 + (flat >> 3);
  const int qblk = wid & 31, bh = wid >> 5;
  const int b = bh >> 4, h = bh & 15;
  const int qbase = qblk * 64;
  const size_t hoff = (size_t)bh * S_LEN * 64;

  bf16x8 qf[2];
#pragma unroll
  for (int kh = 0; kh < 2; kh++)
    qf[kh] = *(const bf16x8*)&Qb[hoff + (size_t)(qbase + w * 16 + lr) * 64 + kh * 32 + g * 8];

  f32x4 o_acc[4];
  float lsum = 0.f;
#pragma unroll
  for (int dg = 0; dg < 4; dg++) o_acc[dg] = (f32x4){0.f, 0.f, 0.f, 0.f};

  const int* maskb = mask + b * S_LEN;
  const int srow = lane >> 3;
  const int sch = (lane & 7) ^ (srow & 7);
  const short* gK = Kb + hoff + (size_t)(w * 16 + srow) * 64 + 8 * sch;
  const short* gV = VbT + hoff + (size_t)(w * 16 + srow) * S_LEN + 8 * sch;

#define STAGEKV(buf, kb)                                                         \
  do {                                                                           \
    _Pragma("unroll") for (int c = 0; c < 2; c++)                                \
        gload16(gK + (size_t)(kb + c * 8) * 64, &Kl[buf][w * 16 + c * 8][0]);    \
    _Pragma("unroll") for (int c = 0; c < 2; c++)                                \
        gload16(gV + (size_t)c * 8 * S_LEN + (kb), &Vl[buf][w * 16 + c * 8][0]); \
  } while (0)

  const int NT = S_LEN / 64;
  STAGEKV(0, 0);
  int buf = 0;

  for (int t = 0; t < NT; t++) {
    const int kb = t * 64;
    __syncthreads();
    if (t + 1 < NT) STAGEKV(buf ^ 1, kb + 64);

    float bias[4][4];
#pragma unroll
    for (int nt = 0; nt < 4; nt++) {
      int4 mv = *(const int4*)&maskb[kb + nt * 16 + 4 * g];
      bias[nt][0] = mv.x ? 0.f : -1e30f;
      bias[nt][1] = mv.y ? 0.f : -1e30f;
      bias[nt][2] = mv.z ? 0.f : -1e30f;
      bias[nt][3] = mv.w ? 0.f : -1e30f;
    }

    f32x4 s[4];
#pragma unroll
    for (int nt = 0; nt < 4; nt++) s[nt] = (f32x4){0.f, 0.f, 0.f, 0.f};
    __builtin_amdgcn_s_setprio(1);
#pragma unroll
    for (int nt = 0; nt < 4; nt++) {
      bf16x8 k0 = *(const bf16x8*)&Kl[buf][nt * 16 + lr][8 * (g ^ (lr & 7))];
      bf16x8 k1 = *(const bf16x8*)&Kl[buf][nt * 16 + lr][8 * ((4 + g) ^ (lr & 7))];
      s[nt] = __builtin_amdgcn_mfma_f32_16x16x32_bf16(k0, qf[0], s[nt], 0, 0, 0);
      s[nt] = __builtin_amdgcn_mfma_f32_16x16x32_bf16(k1, qf[1], s[nt], 0, 0, 0);
    }
    __builtin_amdgcn_s_setprio(0);

    unsigned W0[4], W1[4];
#pragma unroll
    for (int nt = 0; nt < 4; nt++) {
      float p0 = EXP2(s[nt][0] + bias[nt][0]);
      float p1 = EXP2(s[nt][1] + bias[nt][1]);
      float p2 = EXP2(s[nt][2] + bias[nt][2]);
      float p3 = EXP2(s[nt][3] + bias[nt][3]);
      lsum += (p0 + p1) + (p2 + p3);
      W0[nt] = cvt_pk_bf16(p0, p1);
      W1[nt] = cvt_pk_bf16(p2, p3);
    }

    bf16x8 pf[2];
#pragma unroll
    for (int kh = 0; kh < 2; kh++) {
      unsigned a0 = W0[2 * kh], b0 = W0[2 * kh + 1];
      unsigned a1 = W1[2 * kh], b1 = W1[2 * kh + 1];
      pl32swap(a0, b0); pl16swap(a0, b0);
      pl32swap(a1, b1); pl16swap(a1, b1);
      union { unsigned u[4]; bf16x8 v; } pk;
      pk.u[0] = a0; pk.u[1] = a1; pk.u[2] = b0; pk.u[3] = b1;
      pf[kh] = pk.v;
    }

    __builtin_amdgcn_s_setprio(1);
#pragma unroll
    for (int dg = 0; dg < 4; dg++) {
      bf16x8 v0 = *(const bf16x8*)&Vl[buf][dg * 16 + lr][8 * (g ^ (lr & 7))];
      bf16x8 v1 = *(const bf16x8*)&Vl[buf][dg * 16 + lr][8 * ((4 + g) ^ (lr & 7))];
      o_acc[dg] = __builtin_amdgcn_mfma_f32_16x16x32_bf16(pf[0], v0, o_acc[dg], 0, 0, 0);
      o_acc[dg] = __builtin_amdgcn_mfma_f32_16x16x32_bf16(pf[1], v1, o_acc[dg], 0, 0, 0);
    }
    __builtin_amdgcn_s_setprio(0);
    buf ^= 1;
  }
#undef STAGEKV

  {
    float l = lsum;
    l += __shfl_xor(l, 16);
    l += __shfl_xor(l, 32);
    float inv = 1.f / l;
    float invq[4];
#pragma unroll
    for (int r = 0; r < 4; r++) invq[r] = __shfl(inv, 4 * g + r);
#pragma unroll
    for (int dg = 0; dg < 4; dg++)
#pragma unroll
      for (int r = 0; r < 4; r++) {
        int qr = qbase + w * 16 + 4 * g + r;
        int col = h * 64 + dg * 16 + lr;
        Ob[((size_t)b * S_LEN + qr) * DM + col] = f2bf(o_acc[dg][r] * invq[r]);
      }
  }
}

extern "C" void kernel_launch(void* const* d_in, const int* in_sizes, int n_in,
                              void* d_out, int out_size, void* d_ws, size_t ws_size,
                              hipStream_t stream) {
  const float* query = (const float*)d_in[0];
  const float* key   = (const float*)d_in[1];
  const float* value = (const float*)d_in[2];
  const float* Wq = (const float*)d_in[3];
  const float* Wk = (const float*)d_in[4];
  const float* Wv = (const float*)d_in[5];
  const float* Wo = (const float*)d_in[6];
  const int* mask = (const int*)d_in[7];

  char* ws = (char*)d_ws;
  const size_t MB = 1 << 20;
  const bool big = ws_size >= 41 * MB;

  if (big) {
    // xq[0,8) xk[8,16) xv[16,24) Wt[24,30) WoT[30,32) Qb[32,40) Mb[40,+8KB)
    // Kb -> old xq slot (consumed), VbT -> old xk slot, Ob -> old xv slot.
    short* xq  = (short*)(ws);
    short* xk  = (short*)(ws + 8 * MB);
    short* xv  = (short*)(ws + 16 * MB);
    short* WqT = (short*)(ws + 24 * MB);
    short* WkT = (short*)(ws + 26 * MB);
    short* WvT = (short*)(ws + 28 * MB);
    short* WoT = (short*)(ws + 30 * MB);
    short* Qb  = (short*)(ws + 32 * MB);
    short* Mb  = (short*)(ws + 40 * MB);
    short* Kb  = xq;
    short* VbT = xk;
    short* Ob  = xv;

    dim3 tgrid(16, 16, 5);
    wtrans<<<tgrid, 256, 0, stream>>>(Wq, Wk, Wv, Wo, mask, WqT, WkT, WvT, WoT, Mb);
    dim3 cg(1024, 3);
    xcvt<<<cg, 256, 0, stream>>>(query, key, value, xq, xk, xv);

    dim3 gqk(DM / 64, (2 * S_LEN) / 128);  // (16, 32) = 512
    gemm3<3><<<gqk, 256, 0, stream>>>(xq, WqT, Qb, 2 * S_LEN, DM, DM, mask);
    gemm3<1><<<gqk, 256, 0, stream>>>(xk, WkT, Kb, 2 * S_LEN, DM, DM, mask);
    dim3 gv((2 * S_LEN) / 64, DM / 128);   // (64, 8) = 512
    gemm3<4><<<gv, 256, 0, stream>>>(WvT, xv, VbT, DM, 2 * S_LEN, DM, mask);

    dim3 ag(S_LEN / 64, 2 * NHEAD);  // (32, 32) = 1024
    attn10<<<ag, 256, 0, stream>>>(Qb, Kb, VbT, Mb, Ob);

    gemm3<0><<<gqk, 256, 0, stream>>>(Ob, WoT, (float*)d_out, 2 * S_LEN, DM, DM, mask);
  } else {
    short* Qb  = (short*)(ws);
    short* Kb  = (short*)(ws + 8 * MB);
    short* VbT = (short*)(ws + 16 * MB);
    short* WqT = (short*)(ws + 24 * MB);
    short* WkT = (short*)(ws + 26 * MB);
    short* WvT = (short*)(ws + 28 * MB);
    short* Ob  = (short*)(ws + 24 * MB);

    dim3 tgrid(16, 16, 3);
    wtrans<<<tgrid, 256, 0, stream>>>(Wq, Wk, Wv, Wo, mask, WqT, WkT, WvT, WqT, WqT);

    dim3 gq(DM / 64, (2 * S_LEN) / 128);
    gemm2<0, 1, 3><<<gq, 256, 0, stream>>>(query, WqT, Qb, 2 * S_LEN, DM, DM);
    gemm2<0, 1, 1><<<gq, 256, 0, stream>>>(key,   WkT, Kb, 2 * S_LEN, DM, DM);
    dim3 gv((2 * S_LEN) / 64, DM / 128);
    gemm2<1, 0, 2><<<gv, 256, 0, stream>>>(WvT, value, VbT, DM, 2 * S_LEN, DM);

    dim3 ag(S_LEN / 64, 2 * NHEAD);
    attn7<<<ag, 256, 0, stream>>>(Qb, Kb, VbT, mask, Ob);

    gemm2<1, 2, 0><<<gq, 256, 0, stream>>>(Ob, Wo, (float*)d_out, 2 * S_LEN, DM, DM);
  }
}

// Round 13
// 134.481 us; speedup vs baseline: 1.3517x; 1.1034x over previous
//
#include <hip/hip_runtime.h>
#include <hip/hip_bf16.h>

typedef short bf16x8 __attribute__((ext_vector_type(8)));  // 8 bf16 (4 VGPRs)
typedef float f32x4 __attribute__((ext_vector_type(4)));

#define S_LEN 2048
#define NHEAD 16
#define DM 1024

#if __has_builtin(__builtin_amdgcn_exp2f)
#define EXP2(x) __builtin_amdgcn_exp2f(x)
#else
#define EXP2(x) exp2f(x)
#endif

__device__ __forceinline__ short f2bf(float f) {
  union { float f; unsigned u; } x; x.f = f;
  unsigned r = x.u + 0x7fffu + ((x.u >> 16) & 1u);  // RNE
  return (short)(r >> 16);
}

__device__ __forceinline__ unsigned cvt_pk_bf16(float lo, float hi) {
  unsigned r;
  asm("v_cvt_pk_bf16_f32 %0, %1, %2" : "=v"(r) : "v"(lo), "v"(hi));
  return r;
}

__device__ __forceinline__ void pl32swap(unsigned& a, unsigned& b) {
#if __has_builtin(__builtin_amdgcn_permlane32_swap)
  auto r = __builtin_amdgcn_permlane32_swap(a, b, false, false);
  a = r[0]; b = r[1];
#else
  asm volatile("v_permlane32_swap_b32 %0, %1" : "+v"(a), "+v"(b));
#endif
}
__device__ __forceinline__ void pl16swap(unsigned& a, unsigned& b) {
#if __has_builtin(__builtin_amdgcn_permlane16_swap)
  auto r = __builtin_amdgcn_permlane16_swap(a, b, false, false);
  a = r[0]; b = r[1];
#else
  asm volatile("v_permlane16_swap_b32 %0, %1" : "+v"(a), "+v"(b));
#endif
}

__device__ __forceinline__ void gload16(const void* g, void* l) {
  __builtin_amdgcn_global_load_lds(
      (const __attribute__((address_space(1))) void*)g,
      (__attribute__((address_space(3))) void*)l, 16, 0, 0);
}

// ---------------- weight transpose+convert; z==4: mask -> bf16 table Mb
__global__ __launch_bounds__(256) void wtrans(const float* __restrict__ Wq, const float* __restrict__ Wk,
                                              const float* __restrict__ Wv, const float* __restrict__ Wo,
                                              const int* __restrict__ mask,
                                              short* Tq, short* Tk, short* Tv, short* To, short* Mb) {
  const int z = blockIdx.z;
  const int tid = threadIdx.x;
  if (z == 4) {
    if (blockIdx.y == 0 && blockIdx.x < 16) {
      int i = blockIdx.x * 256 + tid;
      Mb[i] = mask[i] ? (short)0x3F80 : (short)0;  // bf16 1.0 / 0.0
    }
    return;
  }
  const float* W = (z == 0) ? Wq : (z == 1) ? Wk : (z == 2) ? Wv : Wo;
  short* T = (z == 0) ? Tq : (z == 1) ? Tk : (z == 2) ? Tv : To;
  __shared__ short Tl[64][72];
  const int k0 = blockIdx.x * 64, n0 = blockIdx.y * 64;
  const int r = tid >> 2, c0 = (tid & 3) * 16;
#pragma unroll
  for (int j = 0; j < 4; j++) {
    float4 v = *(const float4*)&W[(size_t)(k0 + r) * DM + n0 + c0 + 4 * j];
    Tl[r][c0 + 4 * j + 0] = f2bf(v.x);
    Tl[r][c0 + 4 * j + 1] = f2bf(v.y);
    Tl[r][c0 + 4 * j + 2] = f2bf(v.z);
    Tl[r][c0 + 4 * j + 3] = f2bf(v.w);
  }
  __syncthreads();
  bf16x8 o0, o1;
#pragma unroll
  for (int j = 0; j < 8; j++) { o0[j] = Tl[c0 + j][r]; o1[j] = Tl[c0 + 8 + j][r]; }
  *(bf16x8*)&T[(size_t)(n0 + r) * DM + k0 + c0] = o0;
  *(bf16x8*)&T[(size_t)(n0 + r) * DM + k0 + c0 + 8] = o1;
}

// ---------------- x f32 -> bf16 convert (3 tensors)
__global__ __launch_bounds__(256) void xcvt(const float* __restrict__ q, const float* __restrict__ k,
                                            const float* __restrict__ v,
                                            short* xq, short* xk, short* xv) {
  const int z = blockIdx.y;
  const float* src = (z == 0) ? q : (z == 1) ? k : v;
  short* dst = (z == 0) ? xq : (z == 1) ? xk : xv;
  const size_t base = ((size_t)blockIdx.x * 256 + threadIdx.x) * 16;
  float4 a = *(const float4*)&src[base];
  float4 b = *(const float4*)&src[base + 4];
  float4 c = *(const float4*)&src[base + 8];
  float4 d = *(const float4*)&src[base + 12];
  bf16x8 o0, o1;
  o0[0] = f2bf(a.x); o0[1] = f2bf(a.y); o0[2] = f2bf(a.z); o0[3] = f2bf(a.w);
  o0[4] = f2bf(b.x); o0[5] = f2bf(b.y); o0[6] = f2bf(b.z); o0[7] = f2bf(b.w);
  o1[0] = f2bf(c.x); o1[1] = f2bf(c.y); o1[2] = f2bf(c.z); o1[3] = f2bf(c.w);
  o1[4] = f2bf(d.x); o1[5] = f2bf(d.y); o1[6] = f2bf(d.z); o1[7] = f2bf(d.w);
  *(bf16x8*)&dst[base] = o0;
  *(bf16x8*)&dst[base + 8] = o1;
}

// ---------------- gemm3 (round-10 proven): all-bf16, gload_lds dbuf, swizzled
// LDS, XCD swizzle. CM: 0=f32 row-major, 1=bf16 [bh][s][64],
// 3=CM1 scaled (Q), 4=bf16 [bh][64][s] with mask-zeroing (V)
template<int CM>
__global__ __launch_bounds__(256) void gemm3(const short* __restrict__ A, const short* __restrict__ Bt,
                                             void* __restrict__ Cp, int M, int N, int K,
                                             const int* __restrict__ mask) {
  __shared__ __align__(16) short Al[2][128 * 64];
  __shared__ __align__(16) short Bl[2][64 * 64];
  const int tid = threadIdx.x;
  const int lane = tid & 63, w = tid >> 6;
  const int wm = w >> 1, wn = w & 1;
  const int lr = lane & 15, g = lane >> 4;

  const int flat = blockIdx.y * gridDim.x + blockIdx.x;
  const int nwg = gridDim.x * gridDim.y;
  const int wid = (flat & 7) * (nwg >> 3) + (flat >> 3);
  const int bx = wid % gridDim.x, by = wid / gridDim.x;
  const int m0 = by * 128, n0 = bx * 64;

  f32x4 acc[4][2];
#pragma unroll
  for (int i = 0; i < 4; i++)
#pragma unroll
    for (int j = 0; j < 2; j++) acc[i][j] = (f32x4){0.f, 0.f, 0.f, 0.f};

  const int srow = lane >> 3;
  const int sch = (lane & 7) ^ (srow & 7);
  const short* gA = A + (size_t)(m0 + w * 32 + srow) * K + 8 * sch;
  const short* gB = Bt + (size_t)(n0 + w * 16 + srow) * K + 8 * sch;

#define STAGE(buf, kk)                                                              \
  do {                                                                              \
    _Pragma("unroll") for (int c = 0; c < 4; c++)                                   \
        gload16(gA + (size_t)c * 8 * K + (kk), &Al[buf][(w * 32 + c * 8) * 64]);    \
    _Pragma("unroll") for (int c = 0; c < 2; c++)                                   \
        gload16(gB + (size_t)c * 8 * K + (kk), &Bl[buf][(w * 16 + c * 8) * 64]);    \
  } while (0)

  const int nsteps = K >> 6;
  STAGE(0, 0);
  int buf = 0;
  for (int t = 0; t < nsteps; t++) {
    __syncthreads();
    if (t + 1 < nsteps) STAGE(buf ^ 1, (t + 1) << 6);
#pragma unroll
    for (int kc = 0; kc < 2; kc++) {
      bf16x8 af[4], bfr[2];
#pragma unroll
      for (int mt = 0; mt < 4; mt++) {
        int row = wm * 64 + mt * 16 + lr;
        af[mt] = *(const bf16x8*)&Al[buf][row * 64 + 8 * ((kc * 4 + g) ^ (lr & 7))];
      }
#pragma unroll
      for (int nt = 0; nt < 2; nt++) {
        int row = wn * 32 + nt * 16 + lr;
        bfr[nt] = *(const bf16x8*)&Bl[buf][row * 64 + 8 * ((kc * 4 + g) ^ (lr & 7))];
      }
      __builtin_amdgcn_s_setprio(1);
#pragma unroll
      for (int mt = 0; mt < 4; mt++)
#pragma unroll
        for (int nt = 0; nt < 2; nt++)
          acc[mt][nt] = __builtin_amdgcn_mfma_f32_16x16x32_bf16(af[mt], bfr[nt], acc[mt][nt], 0, 0, 0);
      __builtin_amdgcn_s_setprio(0);
    }
    buf ^= 1;
  }
#undef STAGE

#pragma unroll
  for (int mt = 0; mt < 4; mt++)
#pragma unroll
    for (int nt = 0; nt < 2; nt++) {
      if (CM == 0) {
#pragma unroll
        for (int r = 0; r < 4; r++) {
          int row = m0 + wm * 64 + mt * 16 + g * 4 + r;
          int col = n0 + wn * 32 + nt * 16 + lr;
          ((float*)Cp)[(size_t)row * N + col] = acc[mt][nt][r];
        }
      } else if (CM == 1 || CM == 3) {
        const float scale = (CM == 3) ? 0.18033688011f : 1.f;
#pragma unroll
        for (int r = 0; r < 4; r++) {
          int row = m0 + wm * 64 + mt * 16 + g * 4 + r;
          int col = n0 + wn * 32 + nt * 16 + lr;
          int b = row >> 11, s = row & (S_LEN - 1);
          int h = col >> 6, d = col & 63;
          ((short*)Cp)[(((size_t)(b * NHEAD + h)) * S_LEN + s) * 64 + d] = f2bf(acc[mt][nt][r] * scale);
        }
      } else {
#pragma unroll
        for (int r = 0; r < 4; r++) {
          int row = m0 + wm * 64 + mt * 16 + g * 4 + r;
          int col = n0 + wn * 32 + nt * 16 + lr;
          int h = row >> 6, d = row & 63;
          int b = col >> 11, s = col & (S_LEN - 1);
          float v = acc[mt][nt][r];
          if (CM == 4) v = mask[b * S_LEN + s] ? v : 0.f;
          ((short*)Cp)[(((size_t)(b * NHEAD + h)) * 64 + d) * S_LEN + s] = f2bf(v);
        }
      }
    }
}

// ---------------- gemm2 (fallback small-ws path, unchanged)
template<int AM, int BMODE, int CM>
__global__ __launch_bounds__(256) void gemm2(const void* __restrict__ Ap, const void* __restrict__ Bp,
                                             void* __restrict__ Cp, int M, int N, int K) {
  __shared__ __align__(16) short Al[128][72];
  __shared__ __align__(16) short Bl[64][72];
  const int tid = threadIdx.x;
  const int lane = tid & 63, w = tid >> 6;
  const int wm = w >> 1, wn = w & 1;
  const int lr = lane & 15, g = lane >> 4;
  const int m0 = blockIdx.y * 128, n0 = blockIdx.x * 64;

  f32x4 acc[4][2];
#pragma unroll
  for (int i = 0; i < 4; i++)
#pragma unroll
    for (int j = 0; j < 2; j++) acc[i][j] = (f32x4){0.f, 0.f, 0.f, 0.f};

  const int ar = tid >> 1, ac = (tid & 1) * 32;
  const int br = tid >> 2, bc = (tid & 3) * 16;

  float4 la[8]; bf16x8 la8[4];
  float4 lb[4]; bf16x8 lb8[2];

#define LOADA(kk)                                                                        \
  do {                                                                                   \
    if (AM == 0) {                                                                       \
      const float* A = (const float*)Ap;                                                 \
      _Pragma("unroll") for (int j = 0; j < 8; j++)                                      \
          la[j] = *(const float4*)&A[(size_t)(m0 + ar) * K + (kk) + ac + 4 * j];         \
    } else {                                                                             \
      const short* A = (const short*)Ap;                                                 \
      _Pragma("unroll") for (int j = 0; j < 4; j++)                                      \
          la8[j] = *(const bf16x8*)&A[(size_t)(m0 + ar) * K + (kk) + ac + 8 * j];        \
    }                                                                                    \
  } while (0)

#define LOADB(kk)                                                                        \
  do {                                                                                   \
    if (BMODE == 0) {                                                                    \
      const float* B = (const float*)Bp;                                                 \
      _Pragma("unroll") for (int j = 0; j < 4; j++)                                      \
          lb[j] = *(const float4*)&B[(size_t)(n0 + br) * K + (kk) + bc + 4 * j];         \
    } else if (BMODE == 1) {                                                             \
      const short* B = (const short*)Bp;                                                 \
      _Pragma("unroll") for (int j = 0; j < 2; j++)                                      \
          lb8[j] = *(const bf16x8*)&B[(size_t)(n0 + br) * K + (kk) + bc + 8 * j];        \
    } else {                                                                             \
      const float* B = (const float*)Bp;                                                 \
      _Pragma("unroll") for (int j = 0; j < 4; j++)                                      \
          lb[j] = *(const float4*)&B[(size_t)((kk) + br) * N + n0 + bc + 4 * j];         \
    }                                                                                    \
  } while (0)

  const int nsteps = K >> 6;
  LOADA(0); LOADB(0);

  for (int t = 0; t < nsteps; t++) {
    __syncthreads();
    if (AM == 0) {
#pragma unroll
      for (int j = 0; j < 4; j++) {
        float4 v0 = la[2 * j], v1 = la[2 * j + 1];
        bf16x8 tt;
        tt[0] = f2bf(v0.x); tt[1] = f2bf(v0.y); tt[2] = f2bf(v0.z); tt[3] = f2bf(v0.w);
        tt[4] = f2bf(v1.x); tt[5] = f2bf(v1.y); tt[6] = f2bf(v1.z); tt[7] = f2bf(v1.w);
        *(bf16x8*)&Al[ar][ac + 8 * j] = tt;
      }
    } else {
#pragma unroll
      for (int j = 0; j < 4; j++) *(bf16x8*)&Al[ar][ac + 8 * j] = la8[j];
    }
    if (BMODE == 0) {
#pragma unroll
      for (int j = 0; j < 2; j++) {
        float4 v0 = lb[2 * j], v1 = lb[2 * j + 1];
        bf16x8 tt;
        tt[0] = f2bf(v0.x); tt[1] = f2bf(v0.y); tt[2] = f2bf(v0.z); tt[3] = f2bf(v0.w);
        tt[4] = f2bf(v1.x); tt[5] = f2bf(v1.y); tt[6] = f2bf(v1.z); tt[7] = f2bf(v1.w);
        *(bf16x8*)&Bl[br][bc + 8 * j] = tt;
      }
    } else if (BMODE == 1) {
#pragma unroll
      for (int j = 0; j < 2; j++) *(bf16x8*)&Bl[br][bc + 8 * j] = lb8[j];
    } else {
#pragma unroll
      for (int j = 0; j < 4; j++) {
        float4 v = lb[j];
        Bl[bc + 4 * j + 0][br] = f2bf(v.x);
        Bl[bc + 4 * j + 1][br] = f2bf(v.y);
        Bl[bc + 4 * j + 2][br] = f2bf(v.z);
        Bl[bc + 4 * j + 3][br] = f2bf(v.w);
      }
    }
    __syncthreads();
    if (t + 1 < nsteps) { LOADA((t + 1) << 6); LOADB((t + 1) << 6); }
#pragma unroll
    for (int kc = 0; kc < 2; kc++) {
      bf16x8 af[4], bfr[2];
#pragma unroll
      for (int mt = 0; mt < 4; mt++) af[mt] = *(const bf16x8*)&Al[wm * 64 + mt * 16 + lr][kc * 32 + g * 8];
#pragma unroll
      for (int nt = 0; nt < 2; nt++) bfr[nt] = *(const bf16x8*)&Bl[wn * 32 + nt * 16 + lr][kc * 32 + g * 8];
#pragma unroll
      for (int mt = 0; mt < 4; mt++)
#pragma unroll
        for (int nt = 0; nt < 2; nt++)
          acc[mt][nt] = __builtin_amdgcn_mfma_f32_16x16x32_bf16(af[mt], bfr[nt], acc[mt][nt], 0, 0, 0);
    }
  }
#undef LOADA
#undef LOADB

#pragma unroll
  for (int mt = 0; mt < 4; mt++)
#pragma unroll
    for (int nt = 0; nt < 2; nt++)
#pragma unroll
      for (int r = 0; r < 4; r++) {
        int row = m0 + wm * 64 + mt * 16 + g * 4 + r;
        int col = n0 + wn * 32 + nt * 16 + lr;
        if (CM == 0) {
          ((float*)Cp)[(size_t)row * N + col] = acc[mt][nt][r];
        } else if (CM == 1 || CM == 3) {
          float v = (CM == 3) ? acc[mt][nt][r] * 0.18033688011f : acc[mt][nt][r];
          int b = row >> 11, s = row & (S_LEN - 1);
          int h = col >> 6, d = col & 63;
          ((short*)Cp)[(((size_t)(b * NHEAD + h)) * S_LEN + s) * 64 + d] = f2bf(v);
        } else {
          int h = row >> 6, d = row & 63;
          int b = col >> 11, s = col & (S_LEN - 1);
          ((short*)Cp)[(((size_t)(b * NHEAD + h)) * 64 + d) * S_LEN + s] = f2bf(acc[mt][nt][r]);
        }
      }
}

// ---------------- attn11: attn8 shell + 2q x 2k wave split.
// 4 waves = (wq, wk); each wave: 32 q-rows x 32-k slice per 64-tile.
// Per-wave LDS reads halve (K: 2nt x 2kh b128, V: 4dg b128 at wk slice).
// Softmax/PV identical to attn8's verified permlane path (2 nt -> one K=32 pf).
// End-of-kernel: wk=1 partial O,l merged via LDS (once). Mask-free inner loop
// (V pre-zeroed, lsum via MFMA vs Mb in LDS). Q pre-scaled 0.125*log2e.
__global__ __launch_bounds__(256, 3) void attn11(const short* __restrict__ Qb,
                                                 const short* __restrict__ Kb,
                                                 const short* __restrict__ VbT,
                                                 const short* __restrict__ Mb,
                                                 short* __restrict__ Ob) {
  __shared__ __align__(16) short Kl[2][64][64];
  __shared__ __align__(16) short Vl[2][64][64];
  __shared__ __align__(16) short Ml[S_LEN];

  const int tid = threadIdx.x;
  const int lane = tid & 63, w = tid >> 6;
  const int lr = lane & 15, g = lane >> 4;
  const int wq = w >> 1, wk = w & 1;

  const int flat = blockIdx.y * gridDim.x + blockIdx.x;
  const int wid = (flat & 7) * 128 + (flat >> 3);
  const int qblk = wid & 31, bh = wid >> 5;
  const int b = bh >> 4, h = bh & 15;
  const int qbase = qblk * 64;
  const size_t hoff = (size_t)bh * S_LEN * 64;

  // prologue: mask row -> LDS (first __syncthreads publishes it)
  *(bf16x8*)&Ml[tid * 8] = *(const bf16x8*)&Mb[b * S_LEN + tid * 8];

  // Q frags: 32 q-rows (2 x 16-frag), 64 d (2 kh halves)
  bf16x8 qf[2][2];
#pragma unroll
  for (int qfr = 0; qfr < 2; qfr++)
#pragma unroll
    for (int kh = 0; kh < 2; kh++)
      qf[qfr][kh] = *(const bf16x8*)&Qb[hoff + (size_t)(qbase + wq * 32 + qfr * 16 + lr) * 64 + kh * 32 + g * 8];

  f32x4 o_acc[2][4];
  f32x4 o_l[2];
#pragma unroll
  for (int qfr = 0; qfr < 2; qfr++) {
    o_l[qfr] = (f32x4){0.f, 0.f, 0.f, 0.f};
#pragma unroll
    for (int dg = 0; dg < 4; dg++) o_acc[qfr][dg] = (f32x4){0.f, 0.f, 0.f, 0.f};
  }

  const int srow = lane >> 3;
  const int sch = (lane & 7) ^ (srow & 7);
  const short* gK = Kb + hoff + (size_t)(w * 16 + srow) * 64 + 8 * sch;
  const short* gV = VbT + hoff + (size_t)(w * 16 + srow) * S_LEN + 8 * sch;

#define STAGEKV(buf, kb)                                                         \
  do {                                                                           \
    _Pragma("unroll") for (int c = 0; c < 2; c++)                                \
        gload16(gK + (size_t)((kb) + c * 8) * 64, &Kl[buf][w * 16 + c * 8][0]);  \
    _Pragma("unroll") for (int c = 0; c < 2; c++)                                \
        gload16(gV + (size_t)c * 8 * S_LEN + (kb), &Vl[buf][w * 16 + c * 8][0]); \
  } while (0)

  const int NT = S_LEN / 64;
  STAGEKV(0, 0);
  int buf = 0;

  for (int t = 0; t < NT; t++) {
    const int kb = t * 64;
    __syncthreads();  // tile t resident; prior reads of buf^1 done
    if (t + 1 < NT) STAGEKV(buf ^ 1, kb + 64);

    // mask frag for this wave's k-slice (B-operand: k = g*8+j within slice)
    bf16x8 mf = *(const bf16x8*)&Ml[kb + wk * 32 + g * 8];

    // K frags (A-operand of swapped QK): k-rows wk*32 + nt*16 + lr
    bf16x8 kfr[2][2];
#pragma unroll
    for (int nt = 0; nt < 2; nt++)
#pragma unroll
      for (int kh = 0; kh < 2; kh++)
        kfr[nt][kh] = *(const bf16x8*)&Kl[buf][wk * 32 + nt * 16 + lr][8 * ((4 * kh + g) ^ (lr & 7))];

    // V frags (B-operand): V^T[d = dg*16+lr][k-slice wk*32 + g*8 ..]
    bf16x8 vfr[4];
#pragma unroll
    for (int dg = 0; dg < 4; dg++)
      vfr[dg] = *(const bf16x8*)&Vl[buf][dg * 16 + lr][8 * ((4 * wk + g) ^ (lr & 7))];

#pragma unroll
    for (int qfr = 0; qfr < 2; qfr++) {
      // ---- swapped QK^T: lane holds P[q=lr][k = wk*32 + nt*16 + 4g + r]
      f32x4 s[2];
#pragma unroll
      for (int nt = 0; nt < 2; nt++) s[nt] = (f32x4){0.f, 0.f, 0.f, 0.f};
      __builtin_amdgcn_s_setprio(1);
#pragma unroll
      for (int nt = 0; nt < 2; nt++) {
        s[nt] = __builtin_amdgcn_mfma_f32_16x16x32_bf16(kfr[nt][0], qf[qfr][0], s[nt], 0, 0, 0);
        s[nt] = __builtin_amdgcn_mfma_f32_16x16x32_bf16(kfr[nt][1], qf[qfr][1], s[nt], 0, 0, 0);
      }
      __builtin_amdgcn_s_setprio(0);

      // ---- softmax (mask-free) + pack
      unsigned W0[2], W1[2];
#pragma unroll
      for (int nt = 0; nt < 2; nt++) {
        float p0 = EXP2(s[nt][0]);
        float p1 = EXP2(s[nt][1]);
        float p2 = EXP2(s[nt][2]);
        float p3 = EXP2(s[nt][3]);
        W0[nt] = cvt_pk_bf16(p0, p1);
        W1[nt] = cvt_pk_bf16(p2, p3);
      }

      // ---- in-register P redistribution -> A-frag P[q=lr][k = g*8+j] (K=32)
      bf16x8 pf;
      {
        unsigned a0 = W0[0], b0 = W0[1];
        unsigned a1 = W1[0], b1 = W1[1];
        pl32swap(a0, b0); pl16swap(a0, b0);
        pl32swap(a1, b1); pl16swap(a1, b1);
        union { unsigned u[4]; bf16x8 v; } pk;
        pk.u[0] = a0; pk.u[1] = a1; pk.u[2] = b0; pk.u[3] = b1;
        pf = pk.v;
      }

      // ---- PV + masked row-sum via MFMA
      __builtin_amdgcn_s_setprio(1);
#pragma unroll
      for (int dg = 0; dg < 4; dg++)
        o_acc[qfr][dg] = __builtin_amdgcn_mfma_f32_16x16x32_bf16(pf, vfr[dg], o_acc[qfr][dg], 0, 0, 0);
      o_l[qfr] = __builtin_amdgcn_mfma_f32_16x16x32_bf16(pf, mf, o_l[qfr], 0, 0, 0);
      __builtin_amdgcn_s_setprio(0);
    }
    buf ^= 1;
  }
#undef STAGEKV

  // ---- merge the two k-halves via LDS (once), then normalize + store
  __syncthreads();  // all waves done reading K/V tiles
  float* Sf = (float*)&Kl[0][0][0];  // 64q x 64d f32 = 16 KB
  float* Sl = (float*)&Vl[0][0][0];  // 64 f32
  if (wk == 1) {
#pragma unroll
    for (int qfr = 0; qfr < 2; qfr++) {
#pragma unroll
      for (int dg = 0; dg < 4; dg++)
#pragma unroll
        for (int r = 0; r < 4; r++)
          Sf[(wq * 32 + qfr * 16 + 4 * g + r) * 64 + dg * 16 + lr] = o_acc[qfr][dg][r];
      if (lr == 0)
#pragma unroll
        for (int r = 0; r < 4; r++)
          Sl[wq * 32 + qfr * 16 + 4 * g + r] = o_l[qfr][r];
    }
  }
  __syncthreads();
  if (wk == 0) {
#pragma unroll
    for (int qfr = 0; qfr < 2; qfr++)
#pragma unroll
      for (int r = 0; r < 4; r++) {
        int ql = wq * 32 + qfr * 16 + 4 * g + r;
        float l = o_l[qfr][r] + Sl[ql];
        float inv = 1.f / l;
        int qr = qbase + ql;
#pragma unroll
        for (int dg = 0; dg < 4; dg++) {
          float ov = o_acc[qfr][dg][r] + Sf[ql * 64 + dg * 16 + lr];
          Ob[((size_t)b * S_LEN + qr) * DM + h * 64 + dg * 16 + lr] = f2bf(ov * inv);
        }
      }
  }
}

// ---------------- attn7 (small-ws fallback, self-masking, unchanged)
__global__ __launch_bounds__(256, 4) void attn7(const short* __restrict__ Qb,
                                                const short* __restrict__ Kb,
                                                const short* __restrict__ VbT,
                                                const int* __restrict__ mask,
                                                short* __restrict__ Ob) {
  __shared__ __align__(16) short Kl[2][64][64];
  __shared__ __align__(16) short Vl[2][64][64];

  const int tid = threadIdx.x;
  const int lane = tid & 63, w = tid >> 6;
  const int lr = lane & 15, g = lane >> 4;

  const int flat = blockIdx.y * gridDim.x + blockIdx.x;
  const int wid = (flat & 7) * 128 + (flat >> 3);
  const int qblk = wid & 31, bh = wid >> 5;
  const int b = bh >> 4, h = bh & 15;
  const int qbase = qblk * 64;
  const size_t hoff = (size_t)bh * S_LEN * 64;

  bf16x8 qf[2];
#pragma unroll
  for (int kh = 0; kh < 2; kh++)
    qf[kh] = *(const bf16x8*)&Qb[hoff + (size_t)(qbase + w * 16 + lr) * 64 + kh * 32 + g * 8];

  f32x4 o_acc[4];
  float lsum = 0.f;
#pragma unroll
  for (int dg = 0; dg < 4; dg++) o_acc[dg] = (f32x4){0.f, 0.f, 0.f, 0.f};

  const int* maskb = mask + b * S_LEN;
  const int srow = lane >> 3;
  const int sch = (lane & 7) ^ (srow & 7);
  const short* gK = Kb + hoff + (size_t)(w * 16 + srow) * 64 + 8 * sch;
  const short* gV = VbT + hoff + (size_t)(w * 16 + srow) * S_LEN + 8 * sch;

#define STAGEKV(buf, kb)                                                         \
  do {                                                                           \
    _Pragma("unroll") for (int c = 0; c < 2; c++)                                \
        gload16(gK + (size_t)(kb + c * 8) * 64, &Kl[buf][w * 16 + c * 8][0]);    \
    _Pragma("unroll") for (int c = 0; c < 2; c++)                                \
        gload16(gV + (size_t)c * 8 * S_LEN + (kb), &Vl[buf][w * 16 + c * 8][0]); \
  } while (0)

  const int NT = S_LEN / 64;
  STAGEKV(0, 0);
  int buf = 0;

  for (int t = 0; t < NT; t++) {
    const int kb = t * 64;
    __syncthreads();
    if (t + 1 < NT) STAGEKV(buf ^ 1, kb + 64);

    float bias[4][4];
#pragma unroll
    for (int nt = 0; nt < 4; nt++) {
      int4 mv = *(const int4*)&maskb[kb + nt * 16 + 4 * g];
      bias[nt][0] = mv.x ? 0.f : -1e30f;
      bias[nt][1] = mv.y ? 0.f : -1e30f;
      bias[nt][2] = mv.z ? 0.f : -1e30f;
      bias[nt][3] = mv.w ? 0.f : -1e30f;
    }

    f32x4 s[4];
#pragma unroll
    for (int nt = 0; nt < 4; nt++) s[nt] = (f32x4){0.f, 0.f, 0.f, 0.f};
    __builtin_amdgcn_s_setprio(1);
#pragma unroll
    for (int nt = 0; nt < 4; nt++) {
      bf16x8 k0 = *(const bf16x8*)&Kl[buf][nt * 16 + lr][8 * (g ^ (lr & 7))];
      bf16x8 k1 = *(const bf16x8*)&Kl[buf][nt * 16 + lr][8 * ((4 + g) ^ (lr & 7))];
      s[nt] = __builtin_amdgcn_mfma_f32_16x16x32_bf16(k0, qf[0], s[nt], 0, 0, 0);
      s[nt] = __builtin_amdgcn_mfma_f32_16x16x32_bf16(k1, qf[1], s[nt], 0, 0, 0);
    }
    __builtin_amdgcn_s_setprio(0);

    unsigned W0[4], W1[4];
#pragma unroll
    for (int nt = 0; nt < 4; nt++) {
      float p0 = EXP2(s[nt][0] + bias[nt][0]);
      float p1 = EXP2(s[nt][1] + bias[nt][1]);
      float p2 = EXP2(s[nt][2] + bias[nt][2]);
      float p3 = EXP2(s[nt][3] + bias[nt][3]);
      lsum += (p0 + p1) + (p2 + p3);
      W0[nt] = cvt_pk_bf16(p0, p1);
      W1[nt] = cvt_pk_bf16(p2, p3);
    }

    bf16x8 pf[2];
#pragma unroll
    for (int kh = 0; kh < 2; kh++) {
      unsigned a0 = W0[2 * kh], b0 = W0[2 * kh + 1];
      unsigned a1 = W1[2 * kh], b1 = W1[2 * kh + 1];
      pl32swap(a0, b0); pl16swap(a0, b0);
      pl32swap(a1, b1); pl16swap(a1, b1);
      union { unsigned u[4]; bf16x8 v; } pk;
      pk.u[0] = a0; pk.u[1] = a1; pk.u[2] = b0; pk.u[3] = b1;
      pf[kh] = pk.v;
    }

    __builtin_amdgcn_s_setprio(1);
#pragma unroll
    for (int dg = 0; dg < 4; dg++) {
      bf16x8 v0 = *(const bf16x8*)&Vl[buf][dg * 16 + lr][8 * (g ^ (lr & 7))];
      bf16x8 v1 = *(const bf16x8*)&Vl[buf][dg * 16 + lr][8 * ((4 + g) ^ (lr & 7))];
      o_acc[dg] = __builtin_amdgcn_mfma_f32_16x16x32_bf16(pf[0], v0, o_acc[dg], 0, 0, 0);
      o_acc[dg] = __builtin_amdgcn_mfma_f32_16x16x32_bf16(pf[1], v1, o_acc[dg], 0, 0, 0);
    }
    __builtin_amdgcn_s_setprio(0);
    buf ^= 1;
  }
#undef STAGEKV

  {
    float l = lsum;
    l += __shfl_xor(l, 16);
    l += __shfl_xor(l, 32);
    float inv = 1.f / l;
    float invq[4];
#pragma unroll
    for (int r = 0; r < 4; r++) invq[r] = __shfl(inv, 4 * g + r);
#pragma unroll
    for (int dg = 0; dg < 4; dg++)
#pragma unroll
      for (int r = 0; r < 4; r++) {
        int qr = qbase + w * 16 + 4 * g + r;
        int col = h * 64 + dg * 16 + lr;
        Ob[((size_t)b * S_LEN + qr) * DM + col] = f2bf(o_acc[dg][r] * invq[r]);
      }
  }
}

extern "C" void kernel_launch(void* const* d_in, const int* in_sizes, int n_in,
                              void* d_out, int out_size, void* d_ws, size_t ws_size,
                              hipStream_t stream) {
  const float* query = (const float*)d_in[0];
  const float* key   = (const float*)d_in[1];
  const float* value = (const float*)d_in[2];
  const float* Wq = (const float*)d_in[3];
  const float* Wk = (const float*)d_in[4];
  const float* Wv = (const float*)d_in[5];
  const float* Wo = (const float*)d_in[6];
  const int* mask = (const int*)d_in[7];

  char* ws = (char*)d_ws;
  const size_t MB = 1 << 20;
  const bool big = ws_size >= 41 * MB;

  if (big) {
    // xq[0,8) xk[8,16) xv[16,24) Wt[24,30) WoT[30,32) Qb[32,40) Mb[40,+8KB)
    // Kb -> old xq slot (consumed), VbT -> old xk slot, Ob -> old xv slot.
    short* xq  = (short*)(ws);
    short* xk  = (short*)(ws + 8 * MB);
    short* xv  = (short*)(ws + 16 * MB);
    short* WqT = (short*)(ws + 24 * MB);
    short* WkT = (short*)(ws + 26 * MB);
    short* WvT = (short*)(ws + 28 * MB);
    short* WoT = (short*)(ws + 30 * MB);
    short* Qb  = (short*)(ws + 32 * MB);
    short* Mb  = (short*)(ws + 40 * MB);
    short* Kb  = xq;
    short* VbT = xk;
    short* Ob  = xv;

    dim3 tgrid(16, 16, 5);
    wtrans<<<tgrid, 256, 0, stream>>>(Wq, Wk, Wv, Wo, mask, WqT, WkT, WvT, WoT, Mb);
    dim3 cg(1024, 3);
    xcvt<<<cg, 256, 0, stream>>>(query, key, value, xq, xk, xv);

    dim3 gqk(DM / 64, (2 * S_LEN) / 128);  // (16, 32) = 512
    gemm3<3><<<gqk, 256, 0, stream>>>(xq, WqT, Qb, 2 * S_LEN, DM, DM, mask);
    gemm3<1><<<gqk, 256, 0, stream>>>(xk, WkT, Kb, 2 * S_LEN, DM, DM, mask);
    dim3 gv((2 * S_LEN) / 64, DM / 128);   // (64, 8) = 512
    gemm3<4><<<gv, 256, 0, stream>>>(WvT, xv, VbT, DM, 2 * S_LEN, DM, mask);

    dim3 ag(S_LEN / 64, 2 * NHEAD);  // (32, 32) = 1024
    attn11<<<ag, 256, 0, stream>>>(Qb, Kb, VbT, Mb, Ob);

    gemm3<0><<<gqk, 256, 0, stream>>>(Ob, WoT, (float*)d_out, 2 * S_LEN, DM, DM, mask);
  } else {
    short* Qb  = (short*)(ws);
    short* Kb  = (short*)(ws + 8 * MB);
    short* VbT = (short*)(ws + 16 * MB);
    short* WqT = (short*)(ws + 24 * MB);
    short* WkT = (short*)(ws + 26 * MB);
    short* WvT = (short*)(ws + 28 * MB);
    short* Ob  = (short*)(ws + 24 * MB);

    dim3 tgrid(16, 16, 3);
    wtrans<<<tgrid, 256, 0, stream>>>(Wq, Wk, Wv, Wo, mask, WqT, WkT, WvT, WqT, WqT);

    dim3 gq(DM / 64, (2 * S_LEN) / 128);
    gemm2<0, 1, 3><<<gq, 256, 0, stream>>>(query, WqT, Qb, 2 * S_LEN, DM, DM);
    gemm2<0, 1, 1><<<gq, 256, 0, stream>>>(key,   WkT, Kb, 2 * S_LEN, DM, DM);
    dim3 gv((2 * S_LEN) / 64, DM / 128);
    gemm2<1, 0, 2><<<gv, 256, 0, stream>>>(WvT, value, VbT, DM, 2 * S_LEN, DM);

    dim3 ag(S_LEN / 64, 2 * NHEAD);
    attn7<<<ag, 256, 0, stream>>>(Qb, Kb, VbT, mask, Ob);

    gemm2<1, 2, 0><<<gq, 256, 0, stream>>>(Ob, Wo, (float*)d_out, 2 * S_LEN, DM, DM);
  }
}

// Round 14
// 118.557 us; speedup vs baseline: 1.5332x; 1.1343x over previous
//
#include <hip/hip_runtime.h>
#include <hip/hip_bf16.h>

typedef short bf16x8 __attribute__((ext_vector_type(8)));  // 8 bf16 (4 VGPRs)
typedef float f32x4 __attribute__((ext_vector_type(4)));

#define S_LEN 2048
#define NHEAD 16
#define DM 1024

#if __has_builtin(__builtin_amdgcn_exp2f)
#define EXP2(x) __builtin_amdgcn_exp2f(x)
#else
#define EXP2(x) exp2f(x)
#endif

__device__ __forceinline__ short f2bf(float f) {
  union { float f; unsigned u; } x; x.f = f;
  unsigned r = x.u + 0x7fffu + ((x.u >> 16) & 1u);  // RNE
  return (short)(r >> 16);
}

__device__ __forceinline__ unsigned cvt_pk_bf16(float lo, float hi) {
  unsigned r;
  asm("v_cvt_pk_bf16_f32 %0, %1, %2" : "=v"(r) : "v"(lo), "v"(hi));
  return r;
}

__device__ __forceinline__ void pl32swap(unsigned& a, unsigned& b) {
#if __has_builtin(__builtin_amdgcn_permlane32_swap)
  auto r = __builtin_amdgcn_permlane32_swap(a, b, false, false);
  a = r[0]; b = r[1];
#else
  asm volatile("v_permlane32_swap_b32 %0, %1" : "+v"(a), "+v"(b));
#endif
}
__device__ __forceinline__ void pl16swap(unsigned& a, unsigned& b) {
#if __has_builtin(__builtin_amdgcn_permlane16_swap)
  auto r = __builtin_amdgcn_permlane16_swap(a, b, false, false);
  a = r[0]; b = r[1];
#else
  asm volatile("v_permlane16_swap_b32 %0, %1" : "+v"(a), "+v"(b));
#endif
}

__device__ __forceinline__ void gload16(const void* g, void* l) {
  __builtin_amdgcn_global_load_lds(
      (const __attribute__((address_space(1))) void*)g,
      (__attribute__((address_space(3))) void*)l, 16, 0, 0);
}

// ---------------- weight transpose+convert; z==4: mask -> bf16 table Mb
__global__ __launch_bounds__(256) void wtrans(const float* __restrict__ Wq, const float* __restrict__ Wk,
                                              const float* __restrict__ Wv, const float* __restrict__ Wo,
                                              const int* __restrict__ mask,
                                              short* Tq, short* Tk, short* Tv, short* To, short* Mb) {
  const int z = blockIdx.z;
  const int tid = threadIdx.x;
  if (z == 4) {
    if (blockIdx.y == 0 && blockIdx.x < 16) {
      int i = blockIdx.x * 256 + tid;
      Mb[i] = mask[i] ? (short)0x3F80 : (short)0;  // bf16 1.0 / 0.0
    }
    return;
  }
  const float* W = (z == 0) ? Wq : (z == 1) ? Wk : (z == 2) ? Wv : Wo;
  short* T = (z == 0) ? Tq : (z == 1) ? Tk : (z == 2) ? Tv : To;
  __shared__ short Tl[64][72];
  const int k0 = blockIdx.x * 64, n0 = blockIdx.y * 64;
  const int r = tid >> 2, c0 = (tid & 3) * 16;
#pragma unroll
  for (int j = 0; j < 4; j++) {
    float4 v = *(const float4*)&W[(size_t)(k0 + r) * DM + n0 + c0 + 4 * j];
    Tl[r][c0 + 4 * j + 0] = f2bf(v.x);
    Tl[r][c0 + 4 * j + 1] = f2bf(v.y);
    Tl[r][c0 + 4 * j + 2] = f2bf(v.z);
    Tl[r][c0 + 4 * j + 3] = f2bf(v.w);
  }
  __syncthreads();
  bf16x8 o0, o1;
#pragma unroll
  for (int j = 0; j < 8; j++) { o0[j] = Tl[c0 + j][r]; o1[j] = Tl[c0 + 8 + j][r]; }
  *(bf16x8*)&T[(size_t)(n0 + r) * DM + k0 + c0] = o0;
  *(bf16x8*)&T[(size_t)(n0 + r) * DM + k0 + c0 + 8] = o1;
}

// ---------------- x f32 -> bf16 convert (3 tensors)
__global__ __launch_bounds__(256) void xcvt(const float* __restrict__ q, const float* __restrict__ k,
                                            const float* __restrict__ v,
                                            short* xq, short* xk, short* xv) {
  const int z = blockIdx.y;
  const float* src = (z == 0) ? q : (z == 1) ? k : v;
  short* dst = (z == 0) ? xq : (z == 1) ? xk : xv;
  const size_t base = ((size_t)blockIdx.x * 256 + threadIdx.x) * 16;
  float4 a = *(const float4*)&src[base];
  float4 b = *(const float4*)&src[base + 4];
  float4 c = *(const float4*)&src[base + 8];
  float4 d = *(const float4*)&src[base + 12];
  bf16x8 o0, o1;
  o0[0] = f2bf(a.x); o0[1] = f2bf(a.y); o0[2] = f2bf(a.z); o0[3] = f2bf(a.w);
  o0[4] = f2bf(b.x); o0[5] = f2bf(b.y); o0[6] = f2bf(b.z); o0[7] = f2bf(b.w);
  o1[0] = f2bf(c.x); o1[1] = f2bf(c.y); o1[2] = f2bf(c.z); o1[3] = f2bf(c.w);
  o1[4] = f2bf(d.x); o1[5] = f2bf(d.y); o1[6] = f2bf(d.z); o1[7] = f2bf(d.w);
  *(bf16x8*)&dst[base] = o0;
  *(bf16x8*)&dst[base + 8] = o1;
}

// ---------------- gemm5: fused QKV projection, m97-style 128x128 tile,
// single-buffer LDS (32 KB), 2-barrier K-step, 4 waves (2x2, 64x64 each).
// A = [12288][1024] bf16 (xq|xk|xv contiguous); Bt row-block picked by which.
// which = by>>5: 0 -> Qb (scaled 0.125*log2e), 1 -> Kb, 2 -> VbT (transposed,
// mask-zeroed).
__global__ __launch_bounds__(256) void gemm5(const short* __restrict__ A, const short* __restrict__ Wt,
                                             const int* __restrict__ mask,
                                             short* __restrict__ Qb, short* __restrict__ Kb,
                                             short* __restrict__ VbT) {
  __shared__ __align__(16) short Al[128 * 64];
  __shared__ __align__(16) short Bl[128 * 64];
  const int tid = threadIdx.x;
  const int lane = tid & 63, w = tid >> 6;
  const int wm = w >> 1, wn = w & 1;
  const int lr = lane & 15, g = lane >> 4;

  // grid (8, 96) = 768 blocks; XCD-chunked: 96 wids/XCD, 8 n-blocks per panel
  const int flat = blockIdx.y * gridDim.x + blockIdx.x;
  const int wid = (flat & 7) * 96 + (flat >> 3);
  const int bx = wid & 7, by = wid >> 3;
  const int n0 = bx * 128, m0 = by * 128;
  const int which = by >> 5;

  f32x4 acc[4][4];
#pragma unroll
  for (int i = 0; i < 4; i++)
#pragma unroll
    for (int j = 0; j < 4; j++) acc[i][j] = (f32x4){0.f, 0.f, 0.f, 0.f};

  const int srow = lane >> 3;
  const int sch = (lane & 7) ^ (srow & 7);
  const short* gA = A + (size_t)(m0 + w * 32 + srow) * 1024 + 8 * sch;
  const short* gB = Wt + (size_t)(which * 1024 + n0 + w * 32 + srow) * 1024 + 8 * sch;

  // 8 gload16 per thread per stage (4 A rows + 4 B rows)
#define STAGE(kk)                                                                   \
  do {                                                                              \
    _Pragma("unroll") for (int c = 0; c < 4; c++)                                   \
        gload16(gA + (size_t)c * 8 * 1024 + (kk), &Al[(w * 32 + c * 8) * 64]);      \
    _Pragma("unroll") for (int c = 0; c < 4; c++)                                   \
        gload16(gB + (size_t)c * 8 * 1024 + (kk), &Bl[(w * 32 + c * 8) * 64]);      \
  } while (0)

  const int nsteps = 16;  // K=1024 / 64
  STAGE(0);
  for (int t = 0; t < nsteps; t++) {
    __syncthreads();  // staged loads visible (vmcnt drained before barrier)
#pragma unroll
    for (int kc = 0; kc < 2; kc++) {
      bf16x8 af[4], bfr[4];
#pragma unroll
      for (int mt = 0; mt < 4; mt++) {
        int row = wm * 64 + mt * 16 + lr;
        af[mt] = *(const bf16x8*)&Al[row * 64 + 8 * ((kc * 4 + g) ^ (lr & 7))];
      }
#pragma unroll
      for (int nt = 0; nt < 4; nt++) {
        int row = wn * 64 + nt * 16 + lr;
        bfr[nt] = *(const bf16x8*)&Bl[row * 64 + 8 * ((kc * 4 + g) ^ (lr & 7))];
      }
      __builtin_amdgcn_s_setprio(1);
#pragma unroll
      for (int mt = 0; mt < 4; mt++)
#pragma unroll
        for (int nt = 0; nt < 4; nt++)
          acc[mt][nt] = __builtin_amdgcn_mfma_f32_16x16x32_bf16(af[mt], bfr[nt], acc[mt][nt], 0, 0, 0);
      __builtin_amdgcn_s_setprio(0);
    }
    __syncthreads();  // all LDS reads done before overwrite
    if (t + 1 < nsteps) STAGE((t + 1) << 6);
  }
#undef STAGE

#pragma unroll
  for (int mt = 0; mt < 4; mt++)
#pragma unroll
    for (int nt = 0; nt < 4; nt++) {
      const int col = n0 + wn * 64 + nt * 16 + lr;
      const int h = col >> 6, d = col & 63;
      if (which == 2) {
        const int tok = (m0 & 4095) + wm * 64 + mt * 16 + g * 4;  // 4 consecutive s
        const int bb = tok >> 11, s = tok & (S_LEN - 1);
        int4 mv = *(const int4*)&mask[bb * S_LEN + s];
        union { short s4[4]; uint2 u; } pk;
        pk.s4[0] = mv.x ? f2bf(acc[mt][nt][0]) : (short)0;
        pk.s4[1] = mv.y ? f2bf(acc[mt][nt][1]) : (short)0;
        pk.s4[2] = mv.z ? f2bf(acc[mt][nt][2]) : (short)0;
        pk.s4[3] = mv.w ? f2bf(acc[mt][nt][3]) : (short)0;
        *(uint2*)&VbT[(((size_t)(bb * NHEAD + h)) * 64 + d) * S_LEN + s] = pk.u;
      } else {
        short* dst = (which == 0) ? Qb : Kb;
        const float scale = (which == 0) ? 0.18033688011f : 1.f;
#pragma unroll
        for (int r = 0; r < 4; r++) {
          int tok = (m0 & 4095) + wm * 64 + mt * 16 + g * 4 + r;
          int bb = tok >> 11, s = tok & (S_LEN - 1);
          dst[(((size_t)(bb * NHEAD + h)) * S_LEN + s) * 64 + d] = f2bf(acc[mt][nt][r] * scale);
        }
      }
    }
}

// ---------------- gemm3 (round-10 proven): all-bf16, gload_lds dbuf, swizzled
// LDS, XCD swizzle. Used for the final O @ Wo (CM=0).
template<int CM>
__global__ __launch_bounds__(256) void gemm3(const short* __restrict__ A, const short* __restrict__ Bt,
                                             void* __restrict__ Cp, int M, int N, int K,
                                             const int* __restrict__ mask) {
  __shared__ __align__(16) short Al[2][128 * 64];
  __shared__ __align__(16) short Bl[2][64 * 64];
  const int tid = threadIdx.x;
  const int lane = tid & 63, w = tid >> 6;
  const int wm = w >> 1, wn = w & 1;
  const int lr = lane & 15, g = lane >> 4;

  const int flat = blockIdx.y * gridDim.x + blockIdx.x;
  const int nwg = gridDim.x * gridDim.y;
  const int wid = (flat & 7) * (nwg >> 3) + (flat >> 3);
  const int bx = wid % gridDim.x, by = wid / gridDim.x;
  const int m0 = by * 128, n0 = bx * 64;

  f32x4 acc[4][2];
#pragma unroll
  for (int i = 0; i < 4; i++)
#pragma unroll
    for (int j = 0; j < 2; j++) acc[i][j] = (f32x4){0.f, 0.f, 0.f, 0.f};

  const int srow = lane >> 3;
  const int sch = (lane & 7) ^ (srow & 7);
  const short* gA = A + (size_t)(m0 + w * 32 + srow) * K + 8 * sch;
  const short* gB = Bt + (size_t)(n0 + w * 16 + srow) * K + 8 * sch;

#define STAGE(buf, kk)                                                              \
  do {                                                                              \
    _Pragma("unroll") for (int c = 0; c < 4; c++)                                   \
        gload16(gA + (size_t)c * 8 * K + (kk), &Al[buf][(w * 32 + c * 8) * 64]);    \
    _Pragma("unroll") for (int c = 0; c < 2; c++)                                   \
        gload16(gB + (size_t)c * 8 * K + (kk), &Bl[buf][(w * 16 + c * 8) * 64]);    \
  } while (0)

  const int nsteps = K >> 6;
  STAGE(0, 0);
  int buf = 0;
  for (int t = 0; t < nsteps; t++) {
    __syncthreads();
    if (t + 1 < nsteps) STAGE(buf ^ 1, (t + 1) << 6);
#pragma unroll
    for (int kc = 0; kc < 2; kc++) {
      bf16x8 af[4], bfr[2];
#pragma unroll
      for (int mt = 0; mt < 4; mt++) {
        int row = wm * 64 + mt * 16 + lr;
        af[mt] = *(const bf16x8*)&Al[buf][row * 64 + 8 * ((kc * 4 + g) ^ (lr & 7))];
      }
#pragma unroll
      for (int nt = 0; nt < 2; nt++) {
        int row = wn * 32 + nt * 16 + lr;
        bfr[nt] = *(const bf16x8*)&Bl[buf][row * 64 + 8 * ((kc * 4 + g) ^ (lr & 7))];
      }
      __builtin_amdgcn_s_setprio(1);
#pragma unroll
      for (int mt = 0; mt < 4; mt++)
#pragma unroll
        for (int nt = 0; nt < 2; nt++)
          acc[mt][nt] = __builtin_amdgcn_mfma_f32_16x16x32_bf16(af[mt], bfr[nt], acc[mt][nt], 0, 0, 0);
      __builtin_amdgcn_s_setprio(0);
    }
    buf ^= 1;
  }
#undef STAGE

#pragma unroll
  for (int mt = 0; mt < 4; mt++)
#pragma unroll
    for (int nt = 0; nt < 2; nt++) {
      if (CM == 0) {
#pragma unroll
        for (int r = 0; r < 4; r++) {
          int row = m0 + wm * 64 + mt * 16 + g * 4 + r;
          int col = n0 + wn * 32 + nt * 16 + lr;
          ((float*)Cp)[(size_t)row * N + col] = acc[mt][nt][r];
        }
      } else if (CM == 1 || CM == 3) {
        const float scale = (CM == 3) ? 0.18033688011f : 1.f;
#pragma unroll
        for (int r = 0; r < 4; r++) {
          int row = m0 + wm * 64 + mt * 16 + g * 4 + r;
          int col = n0 + wn * 32 + nt * 16 + lr;
          int b = row >> 11, s = row & (S_LEN - 1);
          int h = col >> 6, d = col & 63;
          ((short*)Cp)[(((size_t)(b * NHEAD + h)) * S_LEN + s) * 64 + d] = f2bf(acc[mt][nt][r] * scale);
        }
      } else {
#pragma unroll
        for (int r = 0; r < 4; r++) {
          int row = m0 + wm * 64 + mt * 16 + g * 4 + r;
          int col = n0 + wn * 32 + nt * 16 + lr;
          int h = row >> 6, d = row & 63;
          int b = col >> 11, s = col & (S_LEN - 1);
          float v = acc[mt][nt][r];
          if (CM == 4) v = mask[b * S_LEN + s] ? v : 0.f;
          ((short*)Cp)[(((size_t)(b * NHEAD + h)) * 64 + d) * S_LEN + s] = f2bf(v);
        }
      }
    }
}

// ---------------- gemm2 (fallback small-ws path, unchanged)
template<int AM, int BMODE, int CM>
__global__ __launch_bounds__(256) void gemm2(const void* __restrict__ Ap, const void* __restrict__ Bp,
                                             void* __restrict__ Cp, int M, int N, int K) {
  __shared__ __align__(16) short Al[128][72];
  __shared__ __align__(16) short Bl[64][72];
  const int tid = threadIdx.x;
  const int lane = tid & 63, w = tid >> 6;
  const int wm = w >> 1, wn = w & 1;
  const int lr = lane & 15, g = lane >> 4;
  const int m0 = blockIdx.y * 128, n0 = blockIdx.x * 64;

  f32x4 acc[4][2];
#pragma unroll
  for (int i = 0; i < 4; i++)
#pragma unroll
    for (int j = 0; j < 2; j++) acc[i][j] = (f32x4){0.f, 0.f, 0.f, 0.f};

  const int ar = tid >> 1, ac = (tid & 1) * 32;
  const int br = tid >> 2, bc = (tid & 3) * 16;

  float4 la[8]; bf16x8 la8[4];
  float4 lb[4]; bf16x8 lb8[2];

#define LOADA(kk)                                                                        \
  do {                                                                                   \
    if (AM == 0) {                                                                       \
      const float* A = (const float*)Ap;                                                 \
      _Pragma("unroll") for (int j = 0; j < 8; j++)                                      \
          la[j] = *(const float4*)&A[(size_t)(m0 + ar) * K + (kk) + ac + 4 * j];         \
    } else {                                                                             \
      const short* A = (const short*)Ap;                                                 \
      _Pragma("unroll") for (int j = 0; j < 4; j++)                                      \
          la8[j] = *(const bf16x8*)&A[(size_t)(m0 + ar) * K + (kk) + ac + 8 * j];        \
    }                                                                                    \
  } while (0)

#define LOADB(kk)                                                                        \
  do {                                                                                   \
    if (BMODE == 0) {                                                                    \
      const float* B = (const float*)Bp;                                                 \
      _Pragma("unroll") for (int j = 0; j < 4; j++)                                      \
          lb[j] = *(const float4*)&B[(size_t)(n0 + br) * K + (kk) + bc + 4 * j];         \
    } else if (BMODE == 1) {                                                             \
      const short* B = (const short*)Bp;                                                 \
      _Pragma("unroll") for (int j = 0; j < 2; j++)                                      \
          lb8[j] = *(const bf16x8*)&B[(size_t)(n0 + br) * K + (kk) + bc + 8 * j];        \
    } else {                                                                             \
      const float* B = (const float*)Bp;                                                 \
      _Pragma("unroll") for (int j = 0; j < 4; j++)                                      \
          lb[j] = *(const float4*)&B[(size_t)((kk) + br) * N + n0 + bc + 4 * j];         \
    }                                                                                    \
  } while (0)

  const int nsteps = K >> 6;
  LOADA(0); LOADB(0);

  for (int t = 0; t < nsteps; t++) {
    __syncthreads();
    if (AM == 0) {
#pragma unroll
      for (int j = 0; j < 4; j++) {
        float4 v0 = la[2 * j], v1 = la[2 * j + 1];
        bf16x8 tt;
        tt[0] = f2bf(v0.x); tt[1] = f2bf(v0.y); tt[2] = f2bf(v0.z); tt[3] = f2bf(v0.w);
        tt[4] = f2bf(v1.x); tt[5] = f2bf(v1.y); tt[6] = f2bf(v1.z); tt[7] = f2bf(v1.w);
        *(bf16x8*)&Al[ar][ac + 8 * j] = tt;
      }
    } else {
#pragma unroll
      for (int j = 0; j < 4; j++) *(bf16x8*)&Al[ar][ac + 8 * j] = la8[j];
    }
    if (BMODE == 0) {
#pragma unroll
      for (int j = 0; j < 2; j++) {
        float4 v0 = lb[2 * j], v1 = lb[2 * j + 1];
        bf16x8 tt;
        tt[0] = f2bf(v0.x); tt[1] = f2bf(v0.y); tt[2] = f2bf(v0.z); tt[3] = f2bf(v0.w);
        tt[4] = f2bf(v1.x); tt[5] = f2bf(v1.y); tt[6] = f2bf(v1.z); tt[7] = f2bf(v1.w);
        *(bf16x8*)&Bl[br][bc + 8 * j] = tt;
      }
    } else if (BMODE == 1) {
#pragma unroll
      for (int j = 0; j < 2; j++) *(bf16x8*)&Bl[br][bc + 8 * j] = lb8[j];
    } else {
#pragma unroll
      for (int j = 0; j < 4; j++) {
        float4 v = lb[j];
        Bl[bc + 4 * j + 0][br] = f2bf(v.x);
        Bl[bc + 4 * j + 1][br] = f2bf(v.y);
        Bl[bc + 4 * j + 2][br] = f2bf(v.z);
        Bl[bc + 4 * j + 3][br] = f2bf(v.w);
      }
    }
    __syncthreads();
    if (t + 1 < nsteps) { LOADA((t + 1) << 6); LOADB((t + 1) << 6); }
#pragma unroll
    for (int kc = 0; kc < 2; kc++) {
      bf16x8 af[4], bfr[2];
#pragma unroll
      for (int mt = 0; mt < 4; mt++) af[mt] = *(const bf16x8*)&Al[wm * 64 + mt * 16 + lr][kc * 32 + g * 8];
#pragma unroll
      for (int nt = 0; nt < 2; nt++) bfr[nt] = *(const bf16x8*)&Bl[wn * 32 + nt * 16 + lr][kc * 32 + g * 8];
#pragma unroll
      for (int mt = 0; mt < 4; mt++)
#pragma unroll
        for (int nt = 0; nt < 2; nt++)
          acc[mt][nt] = __builtin_amdgcn_mfma_f32_16x16x32_bf16(af[mt], bfr[nt], acc[mt][nt], 0, 0, 0);
    }
  }
#undef LOADA
#undef LOADB

#pragma unroll
  for (int mt = 0; mt < 4; mt++)
#pragma unroll
    for (int nt = 0; nt < 2; nt++)
#pragma unroll
      for (int r = 0; r < 4; r++) {
        int row = m0 + wm * 64 + mt * 16 + g * 4 + r;
        int col = n0 + wn * 32 + nt * 16 + lr;
        if (CM == 0) {
          ((float*)Cp)[(size_t)row * N + col] = acc[mt][nt][r];
        } else if (CM == 1 || CM == 3) {
          float v = (CM == 3) ? acc[mt][nt][r] * 0.18033688011f : acc[mt][nt][r];
          int b = row >> 11, s = row & (S_LEN - 1);
          int h = col >> 6, d = col & 63;
          ((short*)Cp)[(((size_t)(b * NHEAD + h)) * S_LEN + s) * 64 + d] = f2bf(v);
        } else {
          int h = row >> 6, d = row & 63;
          int b = col >> 11, s = col & (S_LEN - 1);
          ((short*)Cp)[(((size_t)(b * NHEAD + h)) * 64 + d) * S_LEN + s] = f2bf(acc[mt][nt][r]);
        }
      }
}

// ---------------- attn11 (round-13 proven): 2q x 2k wave split, dbuf,
// mask-free inner loop, permlane P redistribution, LDS merge of k-halves.
__global__ __launch_bounds__(256, 3) void attn11(const short* __restrict__ Qb,
                                                 const short* __restrict__ Kb,
                                                 const short* __restrict__ VbT,
                                                 const short* __restrict__ Mb,
                                                 short* __restrict__ Ob) {
  __shared__ __align__(16) short Kl[2][64][64];
  __shared__ __align__(16) short Vl[2][64][64];
  __shared__ __align__(16) short Ml[S_LEN];

  const int tid = threadIdx.x;
  const int lane = tid & 63, w = tid >> 6;
  const int lr = lane & 15, g = lane >> 4;
  const int wq = w >> 1, wk = w & 1;

  const int flat = blockIdx.y * gridDim.x + blockIdx.x;
  const int wid = (flat & 7) * 128 + (flat >> 3);
  const int qblk = wid & 31, bh = wid >> 5;
  const int b = bh >> 4, h = bh & 15;
  const int qbase = qblk * 64;
  const size_t hoff = (size_t)bh * S_LEN * 64;

  *(bf16x8*)&Ml[tid * 8] = *(const bf16x8*)&Mb[b * S_LEN + tid * 8];

  bf16x8 qf[2][2];
#pragma unroll
  for (int qfr = 0; qfr < 2; qfr++)
#pragma unroll
    for (int kh = 0; kh < 2; kh++)
      qf[qfr][kh] = *(const bf16x8*)&Qb[hoff + (size_t)(qbase + wq * 32 + qfr * 16 + lr) * 64 + kh * 32 + g * 8];

  f32x4 o_acc[2][4];
  f32x4 o_l[2];
#pragma unroll
  for (int qfr = 0; qfr < 2; qfr++) {
    o_l[qfr] = (f32x4){0.f, 0.f, 0.f, 0.f};
#pragma unroll
    for (int dg = 0; dg < 4; dg++) o_acc[qfr][dg] = (f32x4){0.f, 0.f, 0.f, 0.f};
  }

  const int srow = lane >> 3;
  const int sch = (lane & 7) ^ (srow & 7);
  const short* gK = Kb + hoff + (size_t)(w * 16 + srow) * 64 + 8 * sch;
  const short* gV = VbT + hoff + (size_t)(w * 16 + srow) * S_LEN + 8 * sch;

#define STAGEKV(buf, kb)                                                         \
  do {                                                                           \
    _Pragma("unroll") for (int c = 0; c < 2; c++)                                \
        gload16(gK + (size_t)((kb) + c * 8) * 64, &Kl[buf][w * 16 + c * 8][0]);  \
    _Pragma("unroll") for (int c = 0; c < 2; c++)                                \
        gload16(gV + (size_t)c * 8 * S_LEN + (kb), &Vl[buf][w * 16 + c * 8][0]); \
  } while (0)

  const int NT = S_LEN / 64;
  STAGEKV(0, 0);
  int buf = 0;

  for (int t = 0; t < NT; t++) {
    const int kb = t * 64;
    __syncthreads();
    if (t + 1 < NT) STAGEKV(buf ^ 1, kb + 64);

    bf16x8 mf = *(const bf16x8*)&Ml[kb + wk * 32 + g * 8];

    bf16x8 kfr[2][2];
#pragma unroll
    for (int nt = 0; nt < 2; nt++)
#pragma unroll
      for (int kh = 0; kh < 2; kh++)
        kfr[nt][kh] = *(const bf16x8*)&Kl[buf][wk * 32 + nt * 16 + lr][8 * ((4 * kh + g) ^ (lr & 7))];

    bf16x8 vfr[4];
#pragma unroll
    for (int dg = 0; dg < 4; dg++)
      vfr[dg] = *(const bf16x8*)&Vl[buf][dg * 16 + lr][8 * ((4 * wk + g) ^ (lr & 7))];

#pragma unroll
    for (int qfr = 0; qfr < 2; qfr++) {
      f32x4 s[2];
#pragma unroll
      for (int nt = 0; nt < 2; nt++) s[nt] = (f32x4){0.f, 0.f, 0.f, 0.f};
      __builtin_amdgcn_s_setprio(1);
#pragma unroll
      for (int nt = 0; nt < 2; nt++) {
        s[nt] = __builtin_amdgcn_mfma_f32_16x16x32_bf16(kfr[nt][0], qf[qfr][0], s[nt], 0, 0, 0);
        s[nt] = __builtin_amdgcn_mfma_f32_16x16x32_bf16(kfr[nt][1], qf[qfr][1], s[nt], 0, 0, 0);
      }
      __builtin_amdgcn_s_setprio(0);

      unsigned W0[2], W1[2];
#pragma unroll
      for (int nt = 0; nt < 2; nt++) {
        float p0 = EXP2(s[nt][0]);
        float p1 = EXP2(s[nt][1]);
        float p2 = EXP2(s[nt][2]);
        float p3 = EXP2(s[nt][3]);
        W0[nt] = cvt_pk_bf16(p0, p1);
        W1[nt] = cvt_pk_bf16(p2, p3);
      }

      bf16x8 pf;
      {
        unsigned a0 = W0[0], b0 = W0[1];
        unsigned a1 = W1[0], b1 = W1[1];
        pl32swap(a0, b0); pl16swap(a0, b0);
        pl32swap(a1, b1); pl16swap(a1, b1);
        union { unsigned u[4]; bf16x8 v; } pk;
        pk.u[0] = a0; pk.u[1] = a1; pk.u[2] = b0; pk.u[3] = b1;
        pf = pk.v;
      }

      __builtin_amdgcn_s_setprio(1);
#pragma unroll
      for (int dg = 0; dg < 4; dg++)
        o_acc[qfr][dg] = __builtin_amdgcn_mfma_f32_16x16x32_bf16(pf, vfr[dg], o_acc[qfr][dg], 0, 0, 0);
      o_l[qfr] = __builtin_amdgcn_mfma_f32_16x16x32_bf16(pf, mf, o_l[qfr], 0, 0, 0);
      __builtin_amdgcn_s_setprio(0);
    }
    buf ^= 1;
  }
#undef STAGEKV

  __syncthreads();
  float* Sf = (float*)&Kl[0][0][0];
  float* Sl = (float*)&Vl[0][0][0];
  if (wk == 1) {
#pragma unroll
    for (int qfr = 0; qfr < 2; qfr++) {
#pragma unroll
      for (int dg = 0; dg < 4; dg++)
#pragma unroll
        for (int r = 0; r < 4; r++)
          Sf[(wq * 32 + qfr * 16 + 4 * g + r) * 64 + dg * 16 + lr] = o_acc[qfr][dg][r];
      if (lr == 0)
#pragma unroll
        for (int r = 0; r < 4; r++)
          Sl[wq * 32 + qfr * 16 + 4 * g + r] = o_l[qfr][r];
    }
  }
  __syncthreads();
  if (wk == 0) {
#pragma unroll
    for (int qfr = 0; qfr < 2; qfr++)
#pragma unroll
      for (int r = 0; r < 4; r++) {
        int ql = wq * 32 + qfr * 16 + 4 * g + r;
        float l = o_l[qfr][r] + Sl[ql];
        float inv = 1.f / l;
        int qr = qbase + ql;
#pragma unroll
        for (int dg = 0; dg < 4; dg++) {
          float ov = o_acc[qfr][dg][r] + Sf[ql * 64 + dg * 16 + lr];
          Ob[((size_t)b * S_LEN + qr) * DM + h * 64 + dg * 16 + lr] = f2bf(ov * inv);
        }
      }
  }
}

// ---------------- attn7 (small-ws fallback, self-masking, unchanged)
__global__ __launch_bounds__(256, 4) void attn7(const short* __restrict__ Qb,
                                                const short* __restrict__ Kb,
                                                const short* __restrict__ VbT,
                                                const int* __restrict__ mask,
                                                short* __restrict__ Ob) {
  __shared__ __align__(16) short Kl[2][64][64];
  __shared__ __align__(16) short Vl[2][64][64];

  const int tid = threadIdx.x;
  const int lane = tid & 63, w = tid >> 6;
  const int lr = lane & 15, g = lane >> 4;

  const int flat = blockIdx.y * gridDim.x + blockIdx.x;
  const int wid = (flat & 7) * 128 + (flat >> 3);
  const int qblk = wid & 31, bh = wid >> 5;
  const int b = bh >> 4, h = bh & 15;
  const int qbase = qblk * 64;
  const size_t hoff = (size_t)bh * S_LEN * 64;

  bf16x8 qf[2];
#pragma unroll
  for (int kh = 0; kh < 2; kh++)
    qf[kh] = *(const bf16x8*)&Qb[hoff + (size_t)(qbase + w * 16 + lr) * 64 + kh * 32 + g * 8];

  f32x4 o_acc[4];
  float lsum = 0.f;
#pragma unroll
  for (int dg = 0; dg < 4; dg++) o_acc[dg] = (f32x4){0.f, 0.f, 0.f, 0.f};

  const int* maskb = mask + b * S_LEN;
  const int srow = lane >> 3;
  const int sch = (lane & 7) ^ (srow & 7);
  const short* gK = Kb + hoff + (size_t)(w * 16 + srow) * 64 + 8 * sch;
  const short* gV = VbT + hoff + (size_t)(w * 16 + srow) * S_LEN + 8 * sch;

#define STAGEKV(buf, kb)                                                         \
  do {                                                                           \
    _Pragma("unroll") for (int c = 0; c < 2; c++)                                \
        gload16(gK + (size_t)(kb + c * 8) * 64, &Kl[buf][w * 16 + c * 8][0]);    \
    _Pragma("unroll") for (int c = 0; c < 2; c++)                                \
        gload16(gV + (size_t)c * 8 * S_LEN + (kb), &Vl[buf][w * 16 + c * 8][0]); \
  } while (0)

  const int NT = S_LEN / 64;
  STAGEKV(0, 0);
  int buf = 0;

  for (int t = 0; t < NT; t++) {
    const int kb = t * 64;
    __syncthreads();
    if (t + 1 < NT) STAGEKV(buf ^ 1, kb + 64);

    float bias[4][4];
#pragma unroll
    for (int nt = 0; nt < 4; nt++) {
      int4 mv = *(const int4*)&maskb[kb + nt * 16 + 4 * g];
      bias[nt][0] = mv.x ? 0.f : -1e30f;
      bias[nt][1] = mv.y ? 0.f : -1e30f;
      bias[nt][2] = mv.z ? 0.f : -1e30f;
      bias[nt][3] = mv.w ? 0.f : -1e30f;
    }

    f32x4 s[4];
#pragma unroll
    for (int nt = 0; nt < 4; nt++) s[nt] = (f32x4){0.f, 0.f, 0.f, 0.f};
    __builtin_amdgcn_s_setprio(1);
#pragma unroll
    for (int nt = 0; nt < 4; nt++) {
      bf16x8 k0 = *(const bf16x8*)&Kl[buf][nt * 16 + lr][8 * (g ^ (lr & 7))];
      bf16x8 k1 = *(const bf16x8*)&Kl[buf][nt * 16 + lr][8 * ((4 + g) ^ (lr & 7))];
      s[nt] = __builtin_amdgcn_mfma_f32_16x16x32_bf16(k0, qf[0], s[nt], 0, 0, 0);
      s[nt] = __builtin_amdgcn_mfma_f32_16x16x32_bf16(k1, qf[1], s[nt], 0, 0, 0);
    }
    __builtin_amdgcn_s_setprio(0);

    unsigned W0[4], W1[4];
#pragma unroll
    for (int nt = 0; nt < 4; nt++) {
      float p0 = EXP2(s[nt][0] + bias[nt][0]);
      float p1 = EXP2(s[nt][1] + bias[nt][1]);
      float p2 = EXP2(s[nt][2] + bias[nt][2]);
      float p3 = EXP2(s[nt][3] + bias[nt][3]);
      lsum += (p0 + p1) + (p2 + p3);
      W0[nt] = cvt_pk_bf16(p0, p1);
      W1[nt] = cvt_pk_bf16(p2, p3);
    }

    bf16x8 pf[2];
#pragma unroll
    for (int kh = 0; kh < 2; kh++) {
      unsigned a0 = W0[2 * kh], b0 = W0[2 * kh + 1];
      unsigned a1 = W1[2 * kh], b1 = W1[2 * kh + 1];
      pl32swap(a0, b0); pl16swap(a0, b0);
      pl32swap(a1, b1); pl16swap(a1, b1);
      union { unsigned u[4]; bf16x8 v; } pk;
      pk.u[0] = a0; pk.u[1] = a1; pk.u[2] = b0; pk.u[3] = b1;
      pf[kh] = pk.v;
    }

    __builtin_amdgcn_s_setprio(1);
#pragma unroll
    for (int dg = 0; dg < 4; dg++) {
      bf16x8 v0 = *(const bf16x8*)&Vl[buf][dg * 16 + lr][8 * (g ^ (lr & 7))];
      bf16x8 v1 = *(const bf16x8*)&Vl[buf][dg * 16 + lr][8 * ((4 + g) ^ (lr & 7))];
      o_acc[dg] = __builtin_amdgcn_mfma_f32_16x16x32_bf16(pf[0], v0, o_acc[dg], 0, 0, 0);
      o_acc[dg] = __builtin_amdgcn_mfma_f32_16x16x32_bf16(pf[1], v1, o_acc[dg], 0, 0, 0);
    }
    __builtin_amdgcn_s_setprio(0);
    buf ^= 1;
  }
#undef STAGEKV

  {
    float l = lsum;
    l += __shfl_xor(l, 16);
    l += __shfl_xor(l, 32);
    float inv = 1.f / l;
    float invq[4];
#pragma unroll
    for (int r = 0; r < 4; r++) invq[r] = __shfl(inv, 4 * g + r);
#pragma unroll
    for (int dg = 0; dg < 4; dg++)
#pragma unroll
      for (int r = 0; r < 4; r++) {
        int qr = qbase + w * 16 + 4 * g + r;
        int col = h * 64 + dg * 16 + lr;
        Ob[((size_t)b * S_LEN + qr) * DM + col] = f2bf(o_acc[dg][r] * invq[r]);
      }
  }
}

extern "C" void kernel_launch(void* const* d_in, const int* in_sizes, int n_in,
                              void* d_out, int out_size, void* d_ws, size_t ws_size,
                              hipStream_t stream) {
  const float* query = (const float*)d_in[0];
  const float* key   = (const float*)d_in[1];
  const float* value = (const float*)d_in[2];
  const float* Wq = (const float*)d_in[3];
  const float* Wk = (const float*)d_in[4];
  const float* Wv = (const float*)d_in[5];
  const float* Wo = (const float*)d_in[6];
  const int* mask = (const int*)d_in[7];

  char* ws = (char*)d_ws;
  const size_t MB = 1 << 20;
  const bool big = ws_size >= 41 * MB;

  if (big) {
    // ws: xA = xq|xk|xv [0,24) (contiguous A for gemm5); Wt [24,30); WoT [30,32);
    //     Qb [32,40); Mb [40,+64KB).
    // d_out (16MB) doubles as scratch: Kb [0,8MB), VbT [8,16MB) — consumed by
    // attn11, then fully overwritten by the final gemm3<0> write of d_out.
    short* xA  = (short*)(ws);
    short* xq  = xA;
    short* xk  = (short*)(ws + 8 * MB);
    short* xv  = (short*)(ws + 16 * MB);
    short* WqT = (short*)(ws + 24 * MB);   // Wt = WqT|WkT|WvT contiguous
    short* WkT = (short*)(ws + 26 * MB);
    short* WvT = (short*)(ws + 28 * MB);
    short* WoT = (short*)(ws + 30 * MB);
    short* Qb  = (short*)(ws + 32 * MB);
    short* Mb  = (short*)(ws + 40 * MB);
    short* Kb  = (short*)d_out;
    short* VbT = (short*)d_out + (size_t)4 * 1024 * 1024;  // +8 MB
    short* Ob  = xv;  // xv consumed by gemm5 before attn11 writes Ob

    dim3 tgrid(16, 16, 5);
    wtrans<<<tgrid, 256, 0, stream>>>(Wq, Wk, Wv, Wo, mask, WqT, WkT, WvT, WoT, Mb);
    dim3 cg(1024, 3);
    xcvt<<<cg, 256, 0, stream>>>(query, key, value, xq, xk, xv);

    dim3 g5(8, 96);  // 768 blocks: 8 n-blocks x 96 m-panels (12288/128)
    gemm5<<<g5, 256, 0, stream>>>(xA, WqT, mask, Qb, Kb, VbT);

    dim3 ag(S_LEN / 64, 2 * NHEAD);  // (32, 32) = 1024
    attn11<<<ag, 256, 0, stream>>>(Qb, Kb, VbT, Mb, Ob);

    dim3 gqk(DM / 64, (2 * S_LEN) / 128);  // (16, 32) = 512
    gemm3<0><<<gqk, 256, 0, stream>>>(Ob, WoT, (float*)d_out, 2 * S_LEN, DM, DM, mask);
  } else {
    short* Qb  = (short*)(ws);
    short* Kb  = (short*)(ws + 8 * MB);
    short* VbT = (short*)(ws + 16 * MB);
    short* WqT = (short*)(ws + 24 * MB);
    short* WkT = (short*)(ws + 26 * MB);
    short* WvT = (short*)(ws + 28 * MB);
    short* Ob  = (short*)(ws + 24 * MB);

    dim3 tgrid(16, 16, 3);
    wtrans<<<tgrid, 256, 0, stream>>>(Wq, Wk, Wv, Wo, mask, WqT, WkT, WvT, WqT, WqT);

    dim3 gq(DM / 64, (2 * S_LEN) / 128);
    gemm2<0, 1, 3><<<gq, 256, 0, stream>>>(query, WqT, Qb, 2 * S_LEN, DM, DM);
    gemm2<0, 1, 1><<<gq, 256, 0, stream>>>(key,   WkT, Kb, 2 * S_LEN, DM, DM);
    dim3 gv((2 * S_LEN) / 64, DM / 128);
    gemm2<1, 0, 2><<<gv, 256, 0, stream>>>(WvT, value, VbT, DM, 2 * S_LEN, DM);

    dim3 ag(S_LEN / 64, 2 * NHEAD);
    attn7<<<ag, 256, 0, stream>>>(Qb, Kb, VbT, mask, Ob);

    gemm2<1, 2, 0><<<gq, 256, 0, stream>>>(Ob, Wo, (float*)d_out, 2 * S_LEN, DM, DM);
  }
}